// Round 14
// baseline (245.518 us; speedup 1.0000x reference)
//
#include <hip/hip_runtime.h>
#include <hip/hip_bf16.h>

// SelfAttentionLayer1D: B=8, N=2048, C=256, F=128, fp32 in/out.
// Round-14 = round-13 (best, 178.7us) with occupancy diets on the two
// streaming kernels (numerics bit-identical):
//   k_score5c: fx staged THROUGH the gs tile buffers (dead after A-frag
//              hoist) + separate 9KB pm -> LDS 70->44KB -> 3 blocks/CU.
//   k_pv7c   : padding 72->68 ushorts (stride 34 dwords; banks (2r+4c)%32,
//              even) -> LDS 55.3->52.2KB -> 3 blocks/CU.
// Lessons kept: (R7/R13) frag loads must be contiguous (LDS-staged or packed);
//               (R9) no big prefetch reg sets across MFMA (spills).
// Fallback path (ws too small): all-fp32 implementation (round-1 verified).

constexpr int Bb = 8, Nn = 2048, Cc = 256, Ff = 128;
constexpr long BNF = (long)Bb * Nn * Ff;
constexpr long BN  = (long)Bb * Nn;

typedef __bf16 bf16x8 __attribute__((ext_vector_type(8)));
typedef float  f32x4  __attribute__((ext_vector_type(4)));

__device__ inline unsigned short f2bf(float x) {
    unsigned u = __float_as_uint(x);
    unsigned r = (u + 0x7fffu + ((u >> 16) & 1u)) >> 16;
    return (unsigned short)r;
}
__device__ inline float bf2f(unsigned short h) {
    return __uint_as_float(((unsigned)h) << 16);
}

// ============================ FAST PATH ============================

// ---- K0a: W -> fragment-packed split bf16. grid (4, 3).
__global__ __launch_bounds__(256) void k_prepw2(
    const float* __restrict__ W0, const float* __restrict__ W1,
    const float* __restrict__ W2,
    ushort* __restrict__ wpkh, ushort* __restrict__ wpkl)
{
    __shared__ float ls[64][132];
    const float* W = (blockIdx.y == 0) ? W0 : (blockIdx.y == 1) ? W1 : W2;
    const int k0 = blockIdx.x * 64;
    const int t = threadIdx.x;
    const float4* src = (const float4*)(W + (size_t)k0 * 128);
    #pragma unroll
    for (int i = 0; i < 8; ++i) {
        int idx = t + 256 * i;
        int r = idx >> 5, c4 = idx & 31;
        *(float4*)&ls[r][c4 * 4] = src[idx];
    }
    __syncthreads();
    const int lane = t & 63, grp = t >> 6;
    const int col = lane & 15, quad = lane >> 4;
    const int kc = blockIdx.x >> 1;
    const int kkb = (blockIdx.x & 1) * 2;
    #pragma unroll
    for (int g = grp; g < 16; g += 4) {
        int kk_sub = g >> 3;
        int ft = g & 7;
        int f = ft * 16 + col;
        __align__(16) ushort hb[8], lb[8];
        #pragma unroll
        for (int j = 0; j < 8; ++j) {
            float v = ls[kk_sub * 32 + quad * 8 + j][f];
            ushort h = f2bf(v);
            hb[j] = h;
            lb[j] = f2bf(v - bf2f(h));
        }
        size_t base = ((((size_t)blockIdx.y * 2 + kc) * 4 + (kkb + kk_sub)) * 8 + ft) * 512 + (size_t)lane * 8;
        *(uint4*)&wpkh[base] = *(const uint4*)&hb[0];
        *(uint4*)&wpkl[base] = *(const uint4*)&lb[0];
    }
}

// ---- K0b: Wv -> fragment-packed split bf16. grid (2).
__global__ __launch_bounds__(256) void k_prepwv2(
    const float* __restrict__ Wv,
    ushort* __restrict__ wvpkh, ushort* __restrict__ wvpkl)
{
    __shared__ float ls[64][132];
    const int k0 = blockIdx.x * 64;
    const int t = threadIdx.x;
    const float4* src = (const float4*)(Wv + (size_t)k0 * 128);
    #pragma unroll
    for (int i = 0; i < 8; ++i) {
        int idx = t + 256 * i;
        int r = idx >> 5, c4 = idx & 31;
        *(float4*)&ls[r][c4 * 4] = src[idx];
    }
    __syncthreads();
    const int lane = t & 63, grp = t >> 6;
    const int col = lane & 15, quad = lane >> 4;
    #pragma unroll
    for (int g = grp; g < 16; g += 4) {
        int kk_sub = g >> 3;
        int ft = g & 7;
        int f = ft * 16 + col;
        __align__(16) ushort hb[8], lb[8];
        #pragma unroll
        for (int j = 0; j < 8; ++j) {
            float v = ls[kk_sub * 32 + quad * 8 + j][f];
            ushort h = f2bf(v);
            hb[j] = h;
            lb[j] = f2bf(v - bf2f(h));
        }
        size_t base = (((size_t)(blockIdx.x * 2 + kk_sub)) * 8 + ft) * 512 + (size_t)lane * 8;
        *(uint4*)&wvpkh[base] = *(const uint4*)&hb[0];
        *(uint4*)&wvpkl[base] = *(const uint4*)&lb[0];
    }
}

// ---- K1: fused projections, K staged in 2 chunks, packed-W frag loads.
__global__ __launch_bounds__(512, 4) void k_projm2b(
    const float* __restrict__ x,
    const ushort* __restrict__ wpkh, const ushort* __restrict__ wpkl,
    const float* __restrict__ b0, const float* __restrict__ b1,
    const float* __restrict__ b2,
    ushort* __restrict__ fxh, ushort* __restrict__ fxl,
    ushort* __restrict__ gxh, ushort* __restrict__ gxl,
    float* __restrict__ hxt)
{
    __shared__ ushort xsh[64][136], xsl[64][136];
    __shared__ ushort pm[64][136];

    const int t = threadIdx.x;
    const long row0 = (long)blockIdx.x * 64;
    const int wid = t >> 6, lane = t & 63;
    const int wy = wid & 1, wx = wid >> 1;
    const int col = lane & 15, quad = lane >> 4;

    f32x4 acc[3][2][2];
    #pragma unroll
    for (int y = 0; y < 3; ++y)
        #pragma unroll
        for (int i = 0; i < 2; ++i)
            #pragma unroll
            for (int j = 0; j < 2; ++j) acc[y][i][j] = (f32x4){0.f, 0.f, 0.f, 0.f};

    for (int kc = 0; kc < 2; ++kc) {
        if (kc) __syncthreads();
        {
            #pragma unroll
            for (int i = 0; i < 4; ++i) {
                int idx = t + 512 * i;
                int r = idx >> 5, c4 = idx & 31;
                float4 v = *(const float4*)&x[(row0 + r) * 256 + kc * 128 + c4 * 4];
                ushort4 h, l;
                h.x = f2bf(v.x); l.x = f2bf(v.x - bf2f(h.x));
                h.y = f2bf(v.y); l.y = f2bf(v.y - bf2f(h.y));
                h.z = f2bf(v.z); l.z = f2bf(v.z - bf2f(h.z));
                h.w = f2bf(v.w); l.w = f2bf(v.w - bf2f(h.w));
                *(ushort4*)&xsh[r][c4 * 4] = h;
                *(ushort4*)&xsl[r][c4 * 4] = l;
            }
        }
        __syncthreads();

        #pragma unroll
        for (int y = 0; y < 3; ++y) {
            #pragma unroll
            for (int kk = 0; kk < 4; ++kk) {
                const int ko = kk * 32 + quad * 8;
                bf16x8 ah[2], al[2], bh[2], bl[2];
                #pragma unroll
                for (int tn = 0; tn < 2; ++tn) {
                    int r = wy * 32 + tn * 16 + col;
                    ah[tn] = *(const bf16x8*)&xsh[r][ko];
                    al[tn] = *(const bf16x8*)&xsl[r][ko];
                }
                #pragma unroll
                for (int tf = 0; tf < 2; ++tf) {
                    size_t base = ((((size_t)y * 2 + kc) * 4 + kk) * 8 + (wx * 2 + tf)) * 512 + (size_t)lane * 8;
                    bh[tf] = *(const bf16x8*)&wpkh[base];
                    bl[tf] = *(const bf16x8*)&wpkl[base];
                }
                #pragma unroll
                for (int tn = 0; tn < 2; ++tn)
                    #pragma unroll
                    for (int tf = 0; tf < 2; ++tf) {
                        acc[y][tn][tf] = __builtin_amdgcn_mfma_f32_16x16x32_bf16(ah[tn], bh[tf], acc[y][tn][tf], 0, 0, 0);
                        acc[y][tn][tf] = __builtin_amdgcn_mfma_f32_16x16x32_bf16(ah[tn], bl[tf], acc[y][tn][tf], 0, 0, 0);
                        acc[y][tn][tf] = __builtin_amdgcn_mfma_f32_16x16x32_bf16(al[tn], bh[tf], acc[y][tn][tf], 0, 0, 0);
                    }
            }
        }
    }

    #pragma unroll
    for (int y = 0; y < 3; ++y) {
        const float* bias = (y == 0) ? b0 : (y == 1) ? b1 : b2;
        float v[2][2][4];
        #pragma unroll
        for (int tf = 0; tf < 2; ++tf) {
            float bb = bias[wx * 32 + tf * 16 + col];
            #pragma unroll
            for (int tn = 0; tn < 2; ++tn)
                #pragma unroll
                for (int r = 0; r < 4; ++r) v[tn][tf][r] = acc[y][tn][tf][r] + bb;
        }

        if (y == 2) {
            float* ob = hxt + (row0 >> 11) * (size_t)128 * 2048;
            int n0 = (int)(row0 & 2047);
            #pragma unroll
            for (int tn = 0; tn < 2; ++tn) {
                int n = n0 + wy * 32 + tn * 16 + quad * 4;
                #pragma unroll
                for (int tf = 0; tf < 2; ++tf) {
                    int f = wx * 32 + tf * 16 + col;
                    f32x4 vv = {v[tn][tf][0], v[tn][tf][1], v[tn][tf][2], v[tn][tf][3]};
                    *(f32x4*)&ob[(size_t)f * 2048 + n] = vv;
                }
            }
        } else {
            ushort* oh = (y == 0) ? fxh : gxh;
            ushort* ol = (y == 0) ? fxl : gxl;
            if (y == 0) __syncthreads();
            #pragma unroll
            for (int tn = 0; tn < 2; ++tn)
                #pragma unroll
                for (int tf = 0; tf < 2; ++tf)
                    #pragma unroll
                    for (int r = 0; r < 4; ++r)
                        pm[wy * 32 + tn * 16 + quad * 4 + r][wx * 32 + tf * 16 + col] = f2bf(v[tn][tf][r]);
            __syncthreads();
            #pragma unroll
            for (int i = 0; i < 2; ++i) {
                int idx = t + 512 * i;
                int r = idx >> 4, c = idx & 15;
                *(uint4*)&oh[(row0 + r) * 128 + c * 8] = *(const uint4*)&pm[r][c * 8];
            }
            __syncthreads();
            #pragma unroll
            for (int tn = 0; tn < 2; ++tn)
                #pragma unroll
                for (int tf = 0; tf < 2; ++tf)
                    #pragma unroll
                    for (int r = 0; r < 4; ++r) {
                        float hv = bf2f(f2bf(v[tn][tf][r]));
                        pm[wy * 32 + tn * 16 + quad * 4 + r][wx * 32 + tf * 16 + col] = f2bf(v[tn][tf][r] - hv);
                    }
            __syncthreads();
            #pragma unroll
            for (int i = 0; i < 2; ++i) {
                int idx = t + 512 * i;
                int r = idx >> 4, c = idx & 15;
                *(uint4*)&ol[(row0 + r) * 128 + c * 8] = *(const uint4*)&pm[r][c * 8];
            }
            __syncthreads();
        }
    }
}

// ---- K2: score; fx staged through gs buffers (dead after A-frag hoist);
// separate 9KB pm -> LDS 44KB -> 3 blocks/CU. grid (BN/64, 2), 512 thr.
__global__ __launch_bounds__(512, 6) void k_score5c(
    const ushort* __restrict__ fxh, const ushort* __restrict__ fxl,
    const ushort* __restrict__ gxh, const ushort* __restrict__ gxl,
    ushort* __restrict__ Pt, float* __restrict__ lsum2)
{
    __shared__ ushort gsh[64][136], gsl[64][136];   // 17.4 KB each
    __shared__ ushort pm[64][72];                   // 9.2 KB
    __shared__ float lsum[64];

    const int t = threadIdx.x;
    const int n0g = blockIdx.x * 64;
    const int ms = blockIdx.y;               // m-split 0..1
    const int b = n0g >> 11;
    const int n0 = n0g & 2047;
    const int wid = t >> 6, lane = t & 63;
    const int wy = wid & 1, wx = wid >> 1;   // wy: n half(32), wx: m quarter(16)
    const int col = lane & 15, quad = lane >> 4;

    {   // stage fx tiles INTO gs buffers (reused for gx after hoist)
        const uint4* sh = (const uint4*)(fxh + (size_t)n0g * 128);
        const uint4* sl = (const uint4*)(fxl + (size_t)n0g * 128);
        #pragma unroll
        for (int i = 0; i < 2; ++i) {
            int idx = t + 512 * i;
            int r = idx >> 4, c = idx & 15;
            *(uint4*)&gsh[r][c * 8] = sh[idx];
            *(uint4*)&gsl[r][c * 8] = sl[idx];
        }
        if (t < 64) lsum[t] = 0.f;
    }
    __syncthreads();

    bf16x8 Ah[4][2], Al[4][2];
    #pragma unroll
    for (int kk = 0; kk < 4; ++kk) {
        const int ko = kk * 32 + quad * 8;
        #pragma unroll
        for (int tn = 0; tn < 2; ++tn) {
            int r = wy * 32 + tn * 16 + col;
            Ah[kk][tn] = *(const bf16x8*)&gsh[r][ko];
            Al[kk][tn] = *(const bf16x8*)&gsl[r][ko];
        }
    }

    float rs[2][4] = {};
    const ushort* gbh = gxh + (size_t)b * 2048 * 128;
    const ushort* gbl = gxl + (size_t)b * 2048 * 128;
    ushort* Pb = Pt + (size_t)b * 2048 * 2048;

    for (int mt = 0; mt < 16; ++mt) {
        const int m0 = ms * 1024 + mt * 64;
        __syncthreads();   // A-frag hoist reads / prev gs MFMA + pm P-store done
        {   // gx m-tile 64 x 128, hi+lo (coalesced)
            const uint4* sh = (const uint4*)(gbh + (size_t)m0 * 128);
            const uint4* sl = (const uint4*)(gbl + (size_t)m0 * 128);
            #pragma unroll
            for (int i = 0; i < 2; ++i) {
                int idx = t + 512 * i;
                int r = idx >> 4, c = idx & 15;
                *(uint4*)&gsh[r][c * 8] = sh[idx];
                *(uint4*)&gsl[r][c * 8] = sl[idx];
            }
        }
        __syncthreads();

        f32x4 acc[2];
        acc[0] = (f32x4){0.f, 0.f, 0.f, 0.f};
        acc[1] = (f32x4){0.f, 0.f, 0.f, 0.f};

        #pragma unroll
        for (int kk = 0; kk < 4; ++kk) {
            const int ko = kk * 32 + quad * 8;
            int r = wx * 16 + col;
            bf16x8 bh = *(const bf16x8*)&gsh[r][ko];
            bf16x8 bl = *(const bf16x8*)&gsl[r][ko];
            #pragma unroll
            for (int tn = 0; tn < 2; ++tn) {
                acc[tn] = __builtin_amdgcn_mfma_f32_16x16x32_bf16(Ah[kk][tn], bh, acc[tn], 0, 0, 0);
                acc[tn] = __builtin_amdgcn_mfma_f32_16x16x32_bf16(Ah[kk][tn], bl, acc[tn], 0, 0, 0);
                acc[tn] = __builtin_amdgcn_mfma_f32_16x16x32_bf16(Al[kk][tn], bh, acc[tn], 0, 0, 0);
            }
        }

        // exp, rowsum partials, P-tile [m][n] into pm
        #pragma unroll
        for (int tn = 0; tn < 2; ++tn) {
            float e0 = __expf(acc[tn][0]);
            float e1 = __expf(acc[tn][1]);
            float e2 = __expf(acc[tn][2]);
            float e3 = __expf(acc[tn][3]);
            rs[tn][0] += e0; rs[tn][1] += e1; rs[tn][2] += e2; rs[tn][3] += e3;
            ushort4 pk;
            pk.x = f2bf(e0); pk.y = f2bf(e1); pk.z = f2bf(e2); pk.w = f2bf(e3);
            int ml = wx * 16 + col;
            int nl = wy * 32 + tn * 16 + quad * 4;
            *(ushort4*)&pm[ml][nl] = pk;
        }
        __syncthreads();
        {   // coalesced P^T store: 64 rows x 64 n
            int r = t >> 3, c = t & 7;
            *(uint4*)&Pb[(size_t)(m0 + r) * 2048 + n0 + c * 8] = *(const uint4*)&pm[r][c * 8];
        }
    }

    #pragma unroll
    for (int off = 1; off < 16; off <<= 1)
        #pragma unroll
        for (int tn = 0; tn < 2; ++tn)
            #pragma unroll
            for (int r = 0; r < 4; ++r) rs[tn][r] += __shfl_xor(rs[tn][r], off);
    if (col == 0) {
        #pragma unroll
        for (int tn = 0; tn < 2; ++tn)
            #pragma unroll
            for (int r = 0; r < 4; ++r)
                atomicAdd(&lsum[wy * 32 + tn * 16 + quad * 4 + r], rs[tn][r]);
    }
    __syncthreads();
    if (t < 64) lsum2[(size_t)ms * BN + n0g + t] = lsum[t];
}

// ---- K3: linv = 1/(lsum2[0]+lsum2[1]). grid BN/256 = 64 blocks.
__global__ __launch_bounds__(256) void k_linv(
    const float* __restrict__ lsum2, float* __restrict__ linv)
{
    const long i = (long)blockIdx.x * 256 + threadIdx.x;
    linv[i] = 1.0f / (lsum2[i] + lsum2[BN + i]);
}

// ---- K4: PV, m-tile 128, split-K x4; pad 68 -> 52.2KB LDS -> 3 blocks/CU.
// H staged from fp32 hxt with linv-scale + hi/lo split in the staging loop.
__global__ __launch_bounds__(256, 3) void k_pv7c(
    const ushort* __restrict__ Pt,
    const float* __restrict__ hxt, const float* __restrict__ linv,
    float* __restrict__ op0, float* __restrict__ op1,
    float* __restrict__ op2, float* __restrict__ op3)
{
    __shared__ ushort ps[128][68];                 // 17.4 KB
    __shared__ ushort hsh[128][68], hsl[128][68];  // 17.4 KB each
    const int t = threadIdx.x;
    const int ks = blockIdx.x & 3;
    const int m0g = (blockIdx.x >> 2) * 128;
    const int b = m0g >> 11, m0 = m0g & 2047;
    const int wx = t >> 6;                 // f quarter(32)
    const int lane = t & 63;
    const int col = lane & 15, quad = lane >> 4;
    const int nbase = ks * 512;

    const ushort* Pb = Pt + ((size_t)b * 2048 + m0) * 2048 + nbase;
    const float* Hx = hxt + (size_t)b * 128 * 2048 + nbase;
    const float* Lv = linv + (size_t)b * 2048 + nbase;

    f32x4 acc[8][2];
    #pragma unroll
    for (int i = 0; i < 8; ++i)
        #pragma unroll
        for (int j = 0; j < 2; ++j) acc[i][j] = (f32x4){0.f, 0.f, 0.f, 0.f};

    for (int nt = 0; nt < 8; ++nt) {
        __syncthreads();   // prev LDS reads done
        {   // stage P (128m x 64n) and H = hxt*linv split (128f x 64n)
            #pragma unroll
            for (int i = 0; i < 4; ++i) {
                int idx = t + 256 * i;
                int r = idx >> 3, c = idx & 7;
                size_t g = (size_t)r * 2048 + nt * 64 + c * 8;
                *(uint4*)&ps[r][c * 8] = *(const uint4*)&Pb[g];
                float4 h0 = *(const float4*)&Hx[g];
                float4 h1 = *(const float4*)&Hx[g + 4];
                float4 l0 = *(const float4*)&Lv[nt * 64 + c * 8];
                float4 l1 = *(const float4*)&Lv[nt * 64 + c * 8 + 4];
                float w[8] = {h0.x * l0.x, h0.y * l0.y, h0.z * l0.z, h0.w * l0.w,
                              h1.x * l1.x, h1.y * l1.y, h1.z * l1.z, h1.w * l1.w};
                __align__(16) ushort hb[8], lb[8];
                #pragma unroll
                for (int j = 0; j < 8; ++j) {
                    ushort h = f2bf(w[j]);
                    hb[j] = h;
                    lb[j] = f2bf(w[j] - bf2f(h));
                }
                *(uint4*)&hsh[r][c * 8] = *(const uint4*)&hb[0];
                *(uint4*)&hsl[r][c * 8] = *(const uint4*)&lb[0];
            }
        }
        __syncthreads();

        #pragma unroll
        for (int kk = 0; kk < 2; ++kk) {
            const int ko = kk * 32 + quad * 8;
            bf16x8 a[8], bh[2], bl[2];
            #pragma unroll
            for (int tm = 0; tm < 8; ++tm)
                a[tm] = *(const bf16x8*)&ps[tm * 16 + col][ko];
            #pragma unroll
            for (int tf = 0; tf < 2; ++tf) {
                int r = wx * 32 + tf * 16 + col;
                bh[tf] = *(const bf16x8*)&hsh[r][ko];
                bl[tf] = *(const bf16x8*)&hsl[r][ko];
            }
            #pragma unroll
            for (int tm = 0; tm < 8; ++tm)
                #pragma unroll
                for (int tf = 0; tf < 2; ++tf) {
                    acc[tm][tf] = __builtin_amdgcn_mfma_f32_16x16x32_bf16(a[tm], bh[tf], acc[tm][tf], 0, 0, 0);
                    acc[tm][tf] = __builtin_amdgcn_mfma_f32_16x16x32_bf16(a[tm], bl[tf], acc[tm][tf], 0, 0, 0);
                }
        }
    }

    float* op = (ks == 0) ? op0 : (ks == 1) ? op1 : (ks == 2) ? op2 : op3;
    float* ob = op + (size_t)b * 128 * 2048;
    #pragma unroll
    for (int tm = 0; tm < 8; ++tm) {
        int m = m0 + tm * 16 + quad * 4;
        #pragma unroll
        for (int tf = 0; tf < 2; ++tf) {
            int f = wx * 32 + tf * 16 + col;
            *(f32x4*)&ob[(size_t)f * 2048 + m] = acc[tm][tf];
        }
    }
}

// ---- K5: out = (op0+op1+op2+op3)_view @ Wv + bv, packed-Wv frag loads.
__global__ __launch_bounds__(512) void k_final_m3b(
    const float* __restrict__ op0, const float* __restrict__ op1,
    const float* __restrict__ op2, const float* __restrict__ op3,
    const ushort* __restrict__ wvpkh, const ushort* __restrict__ wvpkl,
    const float* __restrict__ bv, float* __restrict__ out)
{
    __shared__ ushort ash[64][136], asl[64][136];
    __shared__ float pmf[64][132];
    const int t = threadIdx.x;
    const long row0 = (long)blockIdx.x * 64;
    const int wid = t >> 6, lane = t & 63;
    const int wy = wid & 1, wx = wid >> 1;
    const int col = lane & 15, quad = lane >> 4;

    {   // stage o rows: flat sum of 4 partials, split to bf16
        const float4* s0 = (const float4*)(op0 + row0 * 128);
        const float4* s1 = (const float4*)(op1 + row0 * 128);
        const float4* s2 = (const float4*)(op2 + row0 * 128);
        const float4* s3 = (const float4*)(op3 + row0 * 128);
        #pragma unroll
        for (int i = 0; i < 4; ++i) {
            int idx = t + 512 * i;
            float4 a = s0[idx], bq = s1[idx], cq = s2[idx], dq = s3[idx];
            float v0 = ((a.x + bq.x) + cq.x) + dq.x;
            float v1 = ((a.y + bq.y) + cq.y) + dq.y;
            float v2 = ((a.z + bq.z) + cq.z) + dq.z;
            float v3 = ((a.w + bq.w) + cq.w) + dq.w;
            ushort4 h, l;
            h.x = f2bf(v0); l.x = f2bf(v0 - bf2f(h.x));
            h.y = f2bf(v1); l.y = f2bf(v1 - bf2f(h.y));
            h.z = f2bf(v2); l.z = f2bf(v2 - bf2f(h.z));
            h.w = f2bf(v3); l.w = f2bf(v3 - bf2f(h.w));
            int r = idx >> 5, c4 = idx & 31;
            *(ushort4*)&ash[r][c4 * 4] = h;
            *(ushort4*)&asl[r][c4 * 4] = l;
        }
    }
    __syncthreads();

    f32x4 acc[2][2];
    #pragma unroll
    for (int i = 0; i < 2; ++i)
        #pragma unroll
        for (int j = 0; j < 2; ++j) acc[i][j] = (f32x4){0.f, 0.f, 0.f, 0.f};

    #pragma unroll
    for (int kk = 0; kk < 4; ++kk) {
        const int ko = kk * 32 + quad * 8;
        bf16x8 ah[2], al[2], bh[2], bl[2];
        #pragma unroll
        for (int tn = 0; tn < 2; ++tn) {
            int r = wy * 32 + tn * 16 + col;
            ah[tn] = *(const bf16x8*)&ash[r][ko];
            al[tn] = *(const bf16x8*)&asl[r][ko];
        }
        #pragma unroll
        for (int tf = 0; tf < 2; ++tf) {
            size_t base = (((size_t)kk) * 8 + (wx * 2 + tf)) * 512 + (size_t)lane * 8;
            bh[tf] = *(const bf16x8*)&wvpkh[base];
            bl[tf] = *(const bf16x8*)&wvpkl[base];
        }
        #pragma unroll
        for (int tn = 0; tn < 2; ++tn)
            #pragma unroll
            for (int tf = 0; tf < 2; ++tf) {
                acc[tn][tf] = __builtin_amdgcn_mfma_f32_16x16x32_bf16(ah[tn], bh[tf], acc[tn][tf], 0, 0, 0);
                acc[tn][tf] = __builtin_amdgcn_mfma_f32_16x16x32_bf16(ah[tn], bl[tf], acc[tn][tf], 0, 0, 0);
                acc[tn][tf] = __builtin_amdgcn_mfma_f32_16x16x32_bf16(al[tn], bh[tf], acc[tn][tf], 0, 0, 0);
            }
    }

    #pragma unroll
    for (int tf = 0; tf < 2; ++tf) {
        int f = wx * 32 + tf * 16 + col;
        float bb = bv[f];
        #pragma unroll
        for (int tn = 0; tn < 2; ++tn)
            #pragma unroll
            for (int r = 0; r < 4; ++r)
                pmf[wy * 32 + tn * 16 + quad * 4 + r][f] = acc[tn][tf][r] + bb;
    }
    __syncthreads();
    #pragma unroll
    for (int i = 0; i < 4; ++i) {
        int idx = t + 512 * i;
        int r = idx >> 5, c4 = idx & 31;
        *(float4*)&out[(row0 + r) * 128 + c4 * 4] = *(const float4*)&pmf[r][c4 * 4];
    }
}

// ============================ FALLBACK (fp32, verified round 1) ============================

__global__ __launch_bounds__(256) void k_proj(
    const float* __restrict__ x,
    const float* __restrict__ W0, const float* __restrict__ b0,
    const float* __restrict__ W1, const float* __restrict__ b1,
    const float* __restrict__ W2, const float* __restrict__ b2,
    float* __restrict__ o0, float* __restrict__ o1, float* __restrict__ o2)
{
    const float* W; const float* bias; float* out;
    if (blockIdx.y == 0)      { W = W0; bias = b0; out = o0; }
    else if (blockIdx.y == 1) { W = W1; bias = b1; out = o1; }
    else                      { W = W2; bias = b2; out = o2; }

    __shared__ float xs[32][Cc];
    const int t = threadIdx.x;
    const long row0 = (long)blockIdx.x * 32;
    const float4* xg = (const float4*)(x + row0 * Cc);
    float4* xs4 = (float4*)xs;
    #pragma unroll
    for (int i = 0; i < 8; ++i) xs4[t + 256 * i] = xg[t + 256 * i];
    __syncthreads();

    const int cg = t & 31;
    const int rq = t >> 5;
    float acc[4][4] = {};
    const float4* W4 = (const float4*)W;
    for (int k4 = 0; k4 < Cc / 4; ++k4) {
        float4 av[4];
        #pragma unroll
        for (int i = 0; i < 4; ++i) av[i] = *(const float4*)&xs[4 * rq + i][k4 * 4];
        float4 wv4[4];
        #pragma unroll
        for (int kk = 0; kk < 4; ++kk) wv4[kk] = W4[(size_t)(4 * k4 + kk) * (Ff / 4) + cg];
        #pragma unroll
        for (int kk = 0; kk < 4; ++kk) {
            float4 w = wv4[kk];
            #pragma unroll
            for (int i = 0; i < 4; ++i) {
                float a = (kk == 0) ? av[i].x : (kk == 1) ? av[i].y : (kk == 2) ? av[i].z : av[i].w;
                acc[i][0] += a * w.x; acc[i][1] += a * w.y;
                acc[i][2] += a * w.z; acc[i][3] += a * w.w;
            }
        }
    }
    float4 bb = ((const float4*)bias)[cg];
    #pragma unroll
    for (int i = 0; i < 4; ++i) {
        float4 r;
        r.x = acc[i][0] + bb.x; r.y = acc[i][1] + bb.y;
        r.z = acc[i][2] + bb.z; r.w = acc[i][3] + bb.w;
        ((float4*)(out + (row0 + 4 * rq + i) * Ff))[cg] = r;
    }
}

__global__ __launch_bounds__(256) void k_stats(
    const float* __restrict__ fx, const float* __restrict__ gx,
    float* __restrict__ linv)
{
    __shared__ float fs[64][132];
    __shared__ float gs[128][132];
    const int t = threadIdx.x;
    const int n0 = blockIdx.x * 64;
    const int b = n0 / Nn;
    const float* gxb = gx + (long)b * Nn * Ff;
    {
        const float4* src = (const float4*)(fx + (long)n0 * Ff);
        #pragma unroll
        for (int i = 0; i < 8; ++i) {
            int idx = t + 256 * i;
            int r = idx >> 5, c4 = idx & 31;
            *(float4*)&fs[r][c4 * 4] = src[idx];
        }
    }
    const int ty = t >> 4;
    const int tx = t & 15;
    float lsum[4] = {0.f, 0.f, 0.f, 0.f};
    for (int mt = 0; mt < Nn / 128; ++mt) {
        __syncthreads();
        {
            const float4* src = (const float4*)(gxb + (long)mt * 128 * Ff);
            #pragma unroll
            for (int i = 0; i < 16; ++i) {
                int idx = t + 256 * i;
                int r = idx >> 5, c4 = idx & 31;
                *(float4*)&gs[r][c4 * 4] = src[idx];
            }
        }
        __syncthreads();
        float s[4][8] = {};
        for (int k4 = 0; k4 < 32; ++k4) {
            float4 a[4], g4[8];
            #pragma unroll
            for (int i = 0; i < 4; ++i) a[i] = *(const float4*)&fs[ty + 16 * i][k4 * 4];
            #pragma unroll
            for (int j = 0; j < 8; ++j) g4[j] = *(const float4*)&gs[tx + 16 * j][k4 * 4];
            #pragma unroll
            for (int i = 0; i < 4; ++i)
                #pragma unroll
                for (int j = 0; j < 8; ++j)
                    s[i][j] += a[i].x * g4[j].x + a[i].y * g4[j].y
                             + a[i].z * g4[j].z + a[i].w * g4[j].w;
        }
        #pragma unroll
        for (int i = 0; i < 4; ++i) {
            float e = 0.f;
            #pragma unroll
            for (int j = 0; j < 8; ++j) e += __expf(s[i][j]);
            lsum[i] += e;
        }
    }
    #pragma unroll
    for (int off = 1; off < 16; off <<= 1)
        #pragma unroll
        for (int i = 0; i < 4; ++i) lsum[i] += __shfl_xor(lsum[i], off);
    if (tx == 0)
        #pragma unroll
        for (int i = 0; i < 4; ++i) linv[n0 + ty + 16 * i] = 1.0f / lsum[i];
}

__global__ __launch_bounds__(256) void k_attnpv(
    const float* __restrict__ fx, const float* __restrict__ gx,
    const float* __restrict__ hx, const float* __restrict__ linv,
    float* __restrict__ o)
{
    __shared__ float gs[64][132];
    __shared__ float fs[64][132];
    __shared__ float hs[64][132];
    __shared__ float ps[64][68];
    __shared__ float li[64];
    const int t = threadIdx.x;
    const int m0g = blockIdx.x * 64;
    const int b = m0g / Nn;
    const int m0 = m0g - b * Nn;
    const float* fxb = fx + (long)b * Nn * Ff;
    const float* hxb = hx + (long)b * Nn * Ff;
    {
        const float4* src = (const float4*)(gx + (long)m0g * Ff);
        #pragma unroll
        for (int i = 0; i < 8; ++i) {
            int idx = t + 256 * i;
            int r = idx >> 5, c4 = idx & 31;
            *(float4*)&gs[r][c4 * 4] = src[idx];
        }
    }
    const int ty = t >> 4;
    const int tx = t & 15;
    float acc[4][8] = {};
    for (int nt = 0; nt < Nn / 64; ++nt) {
        __syncthreads();
        {
            const float4* srcf = (const float4*)(fxb + (long)nt * 64 * Ff);
            const float4* srch = (const float4*)(hxb + (long)nt * 64 * Ff);
            #pragma unroll
            for (int i = 0; i < 8; ++i) {
                int idx = t + 256 * i;
                int r = idx >> 5, c4 = idx & 31;
                *(float4*)&fs[r][c4 * 4] = srcf[idx];
                *(float4*)&hs[r][c4 * 4] = srch[idx];
            }
            if (t < 64) li[t] = linv[(long)b * Nn + nt * 64 + t];
        }
        __syncthreads();
        float s[4][4] = {};
        for (int k4 = 0; k4 < 32; ++k4) {
            float4 a[4], g4[4];
            #pragma unroll
            for (int i = 0; i < 4; ++i) a[i] = *(const float4*)&fs[ty + 16 * i][k4 * 4];
            #pragma unroll
            for (int j = 0; j < 4; ++j) g4[j] = *(const float4*)&gs[tx + 16 * j][k4 * 4];
            #pragma unroll
            for (int i = 0; i < 4; ++i)
                #pragma unroll
                for (int j = 0; j < 4; ++j)
                    s[i][j] += a[i].x * g4[j].x + a[i].y * g4[j].y
                             + a[i].z * g4[j].z + a[i].w * g4[j].w;
        }
        #pragma unroll
        for (int i = 0; i < 4; ++i) {
            float lv = li[ty + 16 * i];
            #pragma unroll
            for (int j = 0; j < 4; ++j)
                ps[ty + 16 * i][tx + 16 * j] = __expf(s[i][j]) * lv;
        }
        __syncthreads();
        #pragma unroll 4
        for (int n = 0; n < 64; ++n) {
            float4 h0 = *(const float4*)&hs[n][tx * 8];
            float4 h1 = *(const float4*)&hs[n][tx * 8 + 4];
            float pv[4];
            #pragma unroll
            for (int im = 0; im < 4; ++im) pv[im] = ps[n][ty + 16 * im];
            #pragma unroll
            for (int im = 0; im < 4; ++im) {
                acc[im][0] += pv[im] * h0.x; acc[im][1] += pv[im] * h0.y;
                acc[im][2] += pv[im] * h0.z; acc[im][3] += pv[im] * h0.w;
                acc[im][4] += pv[im] * h1.x; acc[im][5] += pv[im] * h1.y;
                acc[im][6] += pv[im] * h1.z; acc[im][7] += pv[im] * h1.w;
            }
        }
    }
    float* ob = o + (size_t)b * Ff * Nn;
    #pragma unroll
    for (int im = 0; im < 4; ++im) {
        int m = m0 + ty + 16 * im;
        #pragma unroll
        for (int jf = 0; jf < 8; ++jf)
            ob[(size_t)(tx * 8 + jf) * Nn + m] = acc[im][jf];
    }
}

__global__ __launch_bounds__(256) void k_final(
    const float* __restrict__ in2, const float* __restrict__ Wv,
    const float* __restrict__ bv, float* __restrict__ out)
{
    __shared__ float xs[32][132];
    const int t = threadIdx.x;
    const long row0 = (long)blockIdx.x * 32;
    {
        const float4* src = (const float4*)(in2 + row0 * Ff);
        #pragma unroll
        for (int i = 0; i < 4; ++i) {
            int idx = t + 256 * i;
            int r = idx >> 5, c4 = idx & 31;
            *(float4*)&xs[r][c4 * 4] = src[idx];
        }
    }
    __syncthreads();

    const int cg = t & 31;
    const int rq = t >> 5;
    float acc[4][4] = {};
    const float4* W4 = (const float4*)Wv;
    for (int k4 = 0; k4 < 32; ++k4) {
        float4 av[4];
        #pragma unroll
        for (int i = 0; i < 4; ++i) av[i] = *(const float4*)&xs[4 * rq + i][k4 * 4];
        float4 wv4[4];
        #pragma unroll
        for (int kk = 0; kk < 4; ++kk) wv4[kk] = W4[(size_t)(4 * k4 + kk) * 32 + cg];
        #pragma unroll
        for (int kk = 0; kk < 4; ++kk) {
            float4 w = wv4[kk];
            #pragma unroll
            for (int i = 0; i < 4; ++i) {
                float a = (kk == 0) ? av[i].x : (kk == 1) ? av[i].y : (kk == 2) ? av[i].z : av[i].w;
                acc[i][0] += a * w.x; acc[i][1] += a * w.y;
                acc[i][2] += a * w.z; acc[i][3] += a * w.w;
            }
        }
    }
    float4 bb = ((const float4*)bv)[cg];
    #pragma unroll
    for (int i = 0; i < 4; ++i) {
        float4 r;
        r.x = acc[i][0] + bb.x; r.y = acc[i][1] + bb.y;
        r.z = acc[i][2] + bb.z; r.w = acc[i][3] + bb.w;
        ((float4*)(out + (row0 + 4 * rq + i) * Ff))[cg] = r;
    }
}

// ============================ launcher ============================

extern "C" void kernel_launch(void* const* d_in, const int* in_sizes, int n_in,
                              void* d_out, int out_size, void* d_ws, size_t ws_size,
                              hipStream_t stream) {
    const float* x  = (const float*)d_in[0];
    const float* Wf = (const float*)d_in[1];
    const float* bf = (const float*)d_in[2];
    const float* Wg = (const float*)d_in[3];
    const float* bg = (const float*)d_in[4];
    const float* Wh = (const float*)d_in[5];
    const float* bh = (const float*)d_in[6];
    const float* Wv = (const float*)d_in[7];
    const float* bv = (const float*)d_in[8];
    float* out = (float*)d_out;

    const size_t sz_hxt  = (size_t)BNF * 4;
    const size_t sz_linv = (size_t)BN * 4;
    const size_t sz_bf   = (size_t)BNF * 2;
    const size_t sz_Pt   = (size_t)Bb * Nn * Nn * 2;
    const size_t sz_wt   = (size_t)3 * 128 * 256 * 2;
    const size_t sz_wv   = (size_t)128 * 128 * 2;
    const size_t need = sz_hxt + sz_linv + 8 * sz_bf + sz_Pt + 2 * sz_wt + 2 * sz_wv;

    if (ws_size >= need) {
        char* p = (char*)d_ws;
        float* hxt   = (float*)p;            p += sz_hxt;   // alive until k_pv7c
        float* linv  = (float*)p;            p += sz_linv;
        ushort* fxh  = (ushort*)p;           p += sz_bf;
        ushort* fxl  = (ushort*)p;           p += sz_bf;
        ushort* gxh  = (ushort*)p;           p += sz_bf;
        ushort* gxl  = (ushort*)p;           p += sz_bf;
        float* op0   = (float*)p;            p += 2 * sz_bf;  // former hth/htl slots
        /* spare region (2*sz_bf = BNF*4 exactly): lsum2 (128 KB) then op3
           reuses the whole spare (disjoint lifetimes). op1/op2 alias
           fxh+fxl / gxh+gxl (dead after k_score5c). */
        float* lsum2 = (float*)p;
        float* op3   = (float*)p;
        float* op1   = (float*)fxh;
        float* op2   = (float*)gxh;
        p += 2 * sz_bf;
        ushort* wpkh  = (ushort*)p;          p += sz_wt;
        ushort* wpkl  = (ushort*)p;          p += sz_wt;
        ushort* wvpkh = (ushort*)p;          p += sz_wv;
        ushort* wvpkl = (ushort*)p;          p += sz_wv;
        ushort* Pt    = (ushort*)p;

        k_prepw2  <<<dim3(4, 3), 256, 0, stream>>>(Wf, Wg, Wh, wpkh, wpkl);
        k_prepwv2 <<<2, 256, 0, stream>>>(Wv, wvpkh, wvpkl);
        k_projm2b <<<BN / 64, 512, 0, stream>>>(x, wpkh, wpkl, bf, bg, bh,
                                                fxh, fxl, gxh, gxl, hxt);
        k_score5c <<<dim3(BN / 64, 2), 512, 0, stream>>>(fxh, fxl, gxh, gxl, Pt, lsum2);
        k_linv    <<<BN / 256, 256, 0, stream>>>(lsum2, linv);
        k_pv7c    <<<(BN / 128) * 4, 256, 0, stream>>>(Pt, hxt, linv, op0, op1, op2, op3);
        k_final_m3b<<<BN / 64, 512, 0, stream>>>(op0, op1, op2, op3, wvpkh, wvpkl, bv, out);
    } else {
        float* ws   = (float*)d_ws;
        float* fx   = ws;
        float* gx   = fx + BNF;
        float* hx   = gx + BNF;
        float* linv = hx + BNF;
        float* o    = linv + BN;
        k_proj  <<<dim3(BN / 32, 3), 256, 0, stream>>>(x, Wf, bf, Wg, bg, Wh, bh, fx, gx, hx);
        k_stats <<<BN / 64, 256, 0, stream>>>(fx, gx, linv);
        k_attnpv<<<BN / 64, 256, 0, stream>>>(fx, gx, hx, linv, o);
        k_final <<<BN / 32, 256, 0, stream>>>(o, Wv, bv, out);
    }
}

// Round 15
// 188.963 us; speedup vs baseline: 1.2993x; 1.2993x over previous
//
#include <hip/hip_runtime.h>
#include <hip/hip_bf16.h>

// SelfAttentionLayer1D: B=8, N=2048, C=256, F=128, fp32 in/out.
// Round-15 = round-13 (best, 178.7us) + only the k_pv half of round-14's diet:
//   k_score5: round-13 verbatim (launch_bounds(512,4) -> VGPR cap 128; the
//             64-VGPR persistent A-frags fit. R14's (512,6) cap=85 SPILLED
//             them -> FETCH 37->200MB, 94us. Lesson: count persistent VGPRs
//             before raising min-waves.)
//   k_pv7c  : pad 72->68 (52.2KB LDS -> 3 blocks/CU), launch_bounds(256,3)
//             cap ~170 VGPR vs ~100 live - safe.
// Lessons kept: (R7/R13) frag loads contiguous (LDS-staged or packed);
//               (R9/R14) persistent regs vs occupancy caps -> spills.
// Fallback path (ws too small): all-fp32 implementation (round-1 verified).

constexpr int Bb = 8, Nn = 2048, Cc = 256, Ff = 128;
constexpr long BNF = (long)Bb * Nn * Ff;
constexpr long BN  = (long)Bb * Nn;

typedef __bf16 bf16x8 __attribute__((ext_vector_type(8)));
typedef float  f32x4  __attribute__((ext_vector_type(4)));

__device__ inline unsigned short f2bf(float x) {
    unsigned u = __float_as_uint(x);
    unsigned r = (u + 0x7fffu + ((u >> 16) & 1u)) >> 16;
    return (unsigned short)r;
}
__device__ inline float bf2f(unsigned short h) {
    return __uint_as_float(((unsigned)h) << 16);
}

// ============================ FAST PATH ============================

// ---- K0a: W -> fragment-packed split bf16. grid (4, 3).
__global__ __launch_bounds__(256) void k_prepw2(
    const float* __restrict__ W0, const float* __restrict__ W1,
    const float* __restrict__ W2,
    ushort* __restrict__ wpkh, ushort* __restrict__ wpkl)
{
    __shared__ float ls[64][132];
    const float* W = (blockIdx.y == 0) ? W0 : (blockIdx.y == 1) ? W1 : W2;
    const int k0 = blockIdx.x * 64;
    const int t = threadIdx.x;
    const float4* src = (const float4*)(W + (size_t)k0 * 128);
    #pragma unroll
    for (int i = 0; i < 8; ++i) {
        int idx = t + 256 * i;
        int r = idx >> 5, c4 = idx & 31;
        *(float4*)&ls[r][c4 * 4] = src[idx];
    }
    __syncthreads();
    const int lane = t & 63, grp = t >> 6;
    const int col = lane & 15, quad = lane >> 4;
    const int kc = blockIdx.x >> 1;
    const int kkb = (blockIdx.x & 1) * 2;
    #pragma unroll
    for (int g = grp; g < 16; g += 4) {
        int kk_sub = g >> 3;
        int ft = g & 7;
        int f = ft * 16 + col;
        __align__(16) ushort hb[8], lb[8];
        #pragma unroll
        for (int j = 0; j < 8; ++j) {
            float v = ls[kk_sub * 32 + quad * 8 + j][f];
            ushort h = f2bf(v);
            hb[j] = h;
            lb[j] = f2bf(v - bf2f(h));
        }
        size_t base = ((((size_t)blockIdx.y * 2 + kc) * 4 + (kkb + kk_sub)) * 8 + ft) * 512 + (size_t)lane * 8;
        *(uint4*)&wpkh[base] = *(const uint4*)&hb[0];
        *(uint4*)&wpkl[base] = *(const uint4*)&lb[0];
    }
}

// ---- K0b: Wv -> fragment-packed split bf16. grid (2).
__global__ __launch_bounds__(256) void k_prepwv2(
    const float* __restrict__ Wv,
    ushort* __restrict__ wvpkh, ushort* __restrict__ wvpkl)
{
    __shared__ float ls[64][132];
    const int k0 = blockIdx.x * 64;
    const int t = threadIdx.x;
    const float4* src = (const float4*)(Wv + (size_t)k0 * 128);
    #pragma unroll
    for (int i = 0; i < 8; ++i) {
        int idx = t + 256 * i;
        int r = idx >> 5, c4 = idx & 31;
        *(float4*)&ls[r][c4 * 4] = src[idx];
    }
    __syncthreads();
    const int lane = t & 63, grp = t >> 6;
    const int col = lane & 15, quad = lane >> 4;
    #pragma unroll
    for (int g = grp; g < 16; g += 4) {
        int kk_sub = g >> 3;
        int ft = g & 7;
        int f = ft * 16 + col;
        __align__(16) ushort hb[8], lb[8];
        #pragma unroll
        for (int j = 0; j < 8; ++j) {
            float v = ls[kk_sub * 32 + quad * 8 + j][f];
            ushort h = f2bf(v);
            hb[j] = h;
            lb[j] = f2bf(v - bf2f(h));
        }
        size_t base = (((size_t)(blockIdx.x * 2 + kk_sub)) * 8 + ft) * 512 + (size_t)lane * 8;
        *(uint4*)&wvpkh[base] = *(const uint4*)&hb[0];
        *(uint4*)&wvpkl[base] = *(const uint4*)&lb[0];
    }
}

// ---- K1: fused projections, K staged in 2 chunks, packed-W frag loads.
__global__ __launch_bounds__(512, 4) void k_projm2b(
    const float* __restrict__ x,
    const ushort* __restrict__ wpkh, const ushort* __restrict__ wpkl,
    const float* __restrict__ b0, const float* __restrict__ b1,
    const float* __restrict__ b2,
    ushort* __restrict__ fxh, ushort* __restrict__ fxl,
    ushort* __restrict__ gxh, ushort* __restrict__ gxl,
    float* __restrict__ hxt)
{
    __shared__ ushort xsh[64][136], xsl[64][136];
    __shared__ ushort pm[64][136];

    const int t = threadIdx.x;
    const long row0 = (long)blockIdx.x * 64;
    const int wid = t >> 6, lane = t & 63;
    const int wy = wid & 1, wx = wid >> 1;
    const int col = lane & 15, quad = lane >> 4;

    f32x4 acc[3][2][2];
    #pragma unroll
    for (int y = 0; y < 3; ++y)
        #pragma unroll
        for (int i = 0; i < 2; ++i)
            #pragma unroll
            for (int j = 0; j < 2; ++j) acc[y][i][j] = (f32x4){0.f, 0.f, 0.f, 0.f};

    for (int kc = 0; kc < 2; ++kc) {
        if (kc) __syncthreads();
        {
            #pragma unroll
            for (int i = 0; i < 4; ++i) {
                int idx = t + 512 * i;
                int r = idx >> 5, c4 = idx & 31;
                float4 v = *(const float4*)&x[(row0 + r) * 256 + kc * 128 + c4 * 4];
                ushort4 h, l;
                h.x = f2bf(v.x); l.x = f2bf(v.x - bf2f(h.x));
                h.y = f2bf(v.y); l.y = f2bf(v.y - bf2f(h.y));
                h.z = f2bf(v.z); l.z = f2bf(v.z - bf2f(h.z));
                h.w = f2bf(v.w); l.w = f2bf(v.w - bf2f(h.w));
                *(ushort4*)&xsh[r][c4 * 4] = h;
                *(ushort4*)&xsl[r][c4 * 4] = l;
            }
        }
        __syncthreads();

        #pragma unroll
        for (int y = 0; y < 3; ++y) {
            #pragma unroll
            for (int kk = 0; kk < 4; ++kk) {
                const int ko = kk * 32 + quad * 8;
                bf16x8 ah[2], al[2], bh[2], bl[2];
                #pragma unroll
                for (int tn = 0; tn < 2; ++tn) {
                    int r = wy * 32 + tn * 16 + col;
                    ah[tn] = *(const bf16x8*)&xsh[r][ko];
                    al[tn] = *(const bf16x8*)&xsl[r][ko];
                }
                #pragma unroll
                for (int tf = 0; tf < 2; ++tf) {
                    size_t base = ((((size_t)y * 2 + kc) * 4 + kk) * 8 + (wx * 2 + tf)) * 512 + (size_t)lane * 8;
                    bh[tf] = *(const bf16x8*)&wpkh[base];
                    bl[tf] = *(const bf16x8*)&wpkl[base];
                }
                #pragma unroll
                for (int tn = 0; tn < 2; ++tn)
                    #pragma unroll
                    for (int tf = 0; tf < 2; ++tf) {
                        acc[y][tn][tf] = __builtin_amdgcn_mfma_f32_16x16x32_bf16(ah[tn], bh[tf], acc[y][tn][tf], 0, 0, 0);
                        acc[y][tn][tf] = __builtin_amdgcn_mfma_f32_16x16x32_bf16(ah[tn], bl[tf], acc[y][tn][tf], 0, 0, 0);
                        acc[y][tn][tf] = __builtin_amdgcn_mfma_f32_16x16x32_bf16(al[tn], bh[tf], acc[y][tn][tf], 0, 0, 0);
                    }
            }
        }
    }

    #pragma unroll
    for (int y = 0; y < 3; ++y) {
        const float* bias = (y == 0) ? b0 : (y == 1) ? b1 : b2;
        float v[2][2][4];
        #pragma unroll
        for (int tf = 0; tf < 2; ++tf) {
            float bb = bias[wx * 32 + tf * 16 + col];
            #pragma unroll
            for (int tn = 0; tn < 2; ++tn)
                #pragma unroll
                for (int r = 0; r < 4; ++r) v[tn][tf][r] = acc[y][tn][tf][r] + bb;
        }

        if (y == 2) {
            float* ob = hxt + (row0 >> 11) * (size_t)128 * 2048;
            int n0 = (int)(row0 & 2047);
            #pragma unroll
            for (int tn = 0; tn < 2; ++tn) {
                int n = n0 + wy * 32 + tn * 16 + quad * 4;
                #pragma unroll
                for (int tf = 0; tf < 2; ++tf) {
                    int f = wx * 32 + tf * 16 + col;
                    f32x4 vv = {v[tn][tf][0], v[tn][tf][1], v[tn][tf][2], v[tn][tf][3]};
                    *(f32x4*)&ob[(size_t)f * 2048 + n] = vv;
                }
            }
        } else {
            ushort* oh = (y == 0) ? fxh : gxh;
            ushort* ol = (y == 0) ? fxl : gxl;
            if (y == 0) __syncthreads();
            #pragma unroll
            for (int tn = 0; tn < 2; ++tn)
                #pragma unroll
                for (int tf = 0; tf < 2; ++tf)
                    #pragma unroll
                    for (int r = 0; r < 4; ++r)
                        pm[wy * 32 + tn * 16 + quad * 4 + r][wx * 32 + tf * 16 + col] = f2bf(v[tn][tf][r]);
            __syncthreads();
            #pragma unroll
            for (int i = 0; i < 2; ++i) {
                int idx = t + 512 * i;
                int r = idx >> 4, c = idx & 15;
                *(uint4*)&oh[(row0 + r) * 128 + c * 8] = *(const uint4*)&pm[r][c * 8];
            }
            __syncthreads();
            #pragma unroll
            for (int tn = 0; tn < 2; ++tn)
                #pragma unroll
                for (int tf = 0; tf < 2; ++tf)
                    #pragma unroll
                    for (int r = 0; r < 4; ++r) {
                        float hv = bf2f(f2bf(v[tn][tf][r]));
                        pm[wy * 32 + tn * 16 + quad * 4 + r][wx * 32 + tf * 16 + col] = f2bf(v[tn][tf][r] - hv);
                    }
            __syncthreads();
            #pragma unroll
            for (int i = 0; i < 2; ++i) {
                int idx = t + 512 * i;
                int r = idx >> 4, c = idx & 15;
                *(uint4*)&ol[(row0 + r) * 128 + c * 8] = *(const uint4*)&pm[r][c * 8];
            }
            __syncthreads();
        }
    }
}

// ---- K2: score, LDS-staged, m-split x2 (round-8/13 verified). grid (BN/64, 2).
__global__ __launch_bounds__(512, 4) void k_score5(
    const ushort* __restrict__ fxh, const ushort* __restrict__ fxl,
    const ushort* __restrict__ gxh, const ushort* __restrict__ gxl,
    ushort* __restrict__ Pt, float* __restrict__ lsum2)
{
    __shared__ ushort gsh[64][136], gsl[64][136];       // 17.4 KB each
    __shared__ __align__(16) ushort fsbuf[2 * 64 * 136]; // 34.8 KB, reused as pm
    __shared__ float lsum[64];
    ushort* fsh = fsbuf;
    ushort* fsl = fsbuf + 64 * 136;
    ushort* pm  = fsbuf;            // [64][72] after A-frag load

    const int t = threadIdx.x;
    const int n0g = blockIdx.x * 64;
    const int ms = blockIdx.y;               // m-split 0..1
    const int b = n0g >> 11;
    const int n0 = n0g & 2047;
    const int wid = t >> 6, lane = t & 63;
    const int wy = wid & 1, wx = wid >> 1;   // wy: n half(32), wx: m quarter(16)
    const int col = lane & 15, quad = lane >> 4;

    {   // stage fx tiles, then hoist A-frags to registers
        const uint4* sh = (const uint4*)(fxh + (size_t)n0g * 128);
        const uint4* sl = (const uint4*)(fxl + (size_t)n0g * 128);
        #pragma unroll
        for (int i = 0; i < 2; ++i) {
            int idx = t + 512 * i;
            int r = idx >> 4, c = idx & 15;
            *(uint4*)&fsh[r * 136 + c * 8] = sh[idx];
            *(uint4*)&fsl[r * 136 + c * 8] = sl[idx];
        }
        if (t < 64) lsum[t] = 0.f;
    }
    __syncthreads();

    bf16x8 Ah[4][2], Al[4][2];
    #pragma unroll
    for (int kk = 0; kk < 4; ++kk) {
        const int ko = kk * 32 + quad * 8;
        #pragma unroll
        for (int tn = 0; tn < 2; ++tn) {
            int r = wy * 32 + tn * 16 + col;
            Ah[kk][tn] = *(const bf16x8*)&fsh[r * 136 + ko];
            Al[kk][tn] = *(const bf16x8*)&fsl[r * 136 + ko];
        }
    }

    float rs[2][4] = {};
    const ushort* gbh = gxh + (size_t)b * 2048 * 128;
    const ushort* gbl = gxl + (size_t)b * 2048 * 128;
    ushort* Pb = Pt + (size_t)b * 2048 * 2048;

    for (int mt = 0; mt < 16; ++mt) {
        const int m0 = ms * 1024 + mt * 64;
        __syncthreads();   // fs/pm reads done
        {   // gx m-tile 64 x 128, hi+lo (coalesced)
            const uint4* sh = (const uint4*)(gbh + (size_t)m0 * 128);
            const uint4* sl = (const uint4*)(gbl + (size_t)m0 * 128);
            #pragma unroll
            for (int i = 0; i < 2; ++i) {
                int idx = t + 512 * i;
                int r = idx >> 4, c = idx & 15;
                *(uint4*)&gsh[r][c * 8] = sh[idx];
                *(uint4*)&gsl[r][c * 8] = sl[idx];
            }
        }
        __syncthreads();

        f32x4 acc[2];
        acc[0] = (f32x4){0.f, 0.f, 0.f, 0.f};
        acc[1] = (f32x4){0.f, 0.f, 0.f, 0.f};

        #pragma unroll
        for (int kk = 0; kk < 4; ++kk) {
            const int ko = kk * 32 + quad * 8;
            int r = wx * 16 + col;
            bf16x8 bh = *(const bf16x8*)&gsh[r][ko];
            bf16x8 bl = *(const bf16x8*)&gsl[r][ko];
            #pragma unroll
            for (int tn = 0; tn < 2; ++tn) {
                acc[tn] = __builtin_amdgcn_mfma_f32_16x16x32_bf16(Ah[kk][tn], bh, acc[tn], 0, 0, 0);
                acc[tn] = __builtin_amdgcn_mfma_f32_16x16x32_bf16(Ah[kk][tn], bl, acc[tn], 0, 0, 0);
                acc[tn] = __builtin_amdgcn_mfma_f32_16x16x32_bf16(Al[kk][tn], bh, acc[tn], 0, 0, 0);
            }
        }

        // exp, rowsum partials, P-tile [m][n] into pm
        #pragma unroll
        for (int tn = 0; tn < 2; ++tn) {
            float e0 = __expf(acc[tn][0]);
            float e1 = __expf(acc[tn][1]);
            float e2 = __expf(acc[tn][2]);
            float e3 = __expf(acc[tn][3]);
            rs[tn][0] += e0; rs[tn][1] += e1; rs[tn][2] += e2; rs[tn][3] += e3;
            ushort4 pk;
            pk.x = f2bf(e0); pk.y = f2bf(e1); pk.z = f2bf(e2); pk.w = f2bf(e3);
            int ml = wx * 16 + col;
            int nl = wy * 32 + tn * 16 + quad * 4;
            *(ushort4*)&pm[ml * 72 + nl] = pk;
        }
        __syncthreads();
        {   // coalesced P^T store: 64 rows x 64 n
            int r = t >> 3, c = t & 7;
            *(uint4*)&Pb[(size_t)(m0 + r) * 2048 + n0 + c * 8] = *(const uint4*)&pm[r * 72 + c * 8];
        }
    }

    #pragma unroll
    for (int off = 1; off < 16; off <<= 1)
        #pragma unroll
        for (int tn = 0; tn < 2; ++tn)
            #pragma unroll
            for (int r = 0; r < 4; ++r) rs[tn][r] += __shfl_xor(rs[tn][r], off);
    if (col == 0) {
        #pragma unroll
        for (int tn = 0; tn < 2; ++tn)
            #pragma unroll
            for (int r = 0; r < 4; ++r)
                atomicAdd(&lsum[wy * 32 + tn * 16 + quad * 4 + r], rs[tn][r]);
    }
    __syncthreads();
    if (t < 64) lsum2[(size_t)ms * BN + n0g + t] = lsum[t];
}

// ---- K3: linv = 1/(lsum2[0]+lsum2[1]). grid BN/256 = 64 blocks.
__global__ __launch_bounds__(256) void k_linv(
    const float* __restrict__ lsum2, float* __restrict__ linv)
{
    const long i = (long)blockIdx.x * 256 + threadIdx.x;
    linv[i] = 1.0f / (lsum2[i] + lsum2[BN + i]);
}

// ---- K4: PV, m-tile 128, split-K x4; pad 68 -> 52.2KB LDS -> 3 blocks/CU.
// launch_bounds(256,3): VGPR cap ~170 vs ~100 live (no spill).
__global__ __launch_bounds__(256, 3) void k_pv7c(
    const ushort* __restrict__ Pt,
    const float* __restrict__ hxt, const float* __restrict__ linv,
    float* __restrict__ op0, float* __restrict__ op1,
    float* __restrict__ op2, float* __restrict__ op3)
{
    __shared__ ushort ps[128][68];                 // 17.4 KB
    __shared__ ushort hsh[128][68], hsl[128][68];  // 17.4 KB each
    const int t = threadIdx.x;
    const int ks = blockIdx.x & 3;
    const int m0g = (blockIdx.x >> 2) * 128;
    const int b = m0g >> 11, m0 = m0g & 2047;
    const int wx = t >> 6;                 // f quarter(32)
    const int lane = t & 63;
    const int col = lane & 15, quad = lane >> 4;
    const int nbase = ks * 512;

    const ushort* Pb = Pt + ((size_t)b * 2048 + m0) * 2048 + nbase;
    const float* Hx = hxt + (size_t)b * 128 * 2048 + nbase;
    const float* Lv = linv + (size_t)b * 2048 + nbase;

    f32x4 acc[8][2];
    #pragma unroll
    for (int i = 0; i < 8; ++i)
        #pragma unroll
        for (int j = 0; j < 2; ++j) acc[i][j] = (f32x4){0.f, 0.f, 0.f, 0.f};

    for (int nt = 0; nt < 8; ++nt) {
        __syncthreads();   // prev LDS reads done
        {   // stage P (128m x 64n) and H = hxt*linv split (128f x 64n)
            #pragma unroll
            for (int i = 0; i < 4; ++i) {
                int idx = t + 256 * i;
                int r = idx >> 3, c = idx & 7;
                size_t g = (size_t)r * 2048 + nt * 64 + c * 8;
                *(uint4*)&ps[r][c * 8] = *(const uint4*)&Pb[g];
                float4 h0 = *(const float4*)&Hx[g];
                float4 h1 = *(const float4*)&Hx[g + 4];
                float4 l0 = *(const float4*)&Lv[nt * 64 + c * 8];
                float4 l1 = *(const float4*)&Lv[nt * 64 + c * 8 + 4];
                float w[8] = {h0.x * l0.x, h0.y * l0.y, h0.z * l0.z, h0.w * l0.w,
                              h1.x * l1.x, h1.y * l1.y, h1.z * l1.z, h1.w * l1.w};
                __align__(16) ushort hb[8], lb[8];
                #pragma unroll
                for (int j = 0; j < 8; ++j) {
                    ushort h = f2bf(w[j]);
                    hb[j] = h;
                    lb[j] = f2bf(w[j] - bf2f(h));
                }
                *(uint4*)&hsh[r][c * 8] = *(const uint4*)&hb[0];
                *(uint4*)&hsl[r][c * 8] = *(const uint4*)&lb[0];
            }
        }
        __syncthreads();

        #pragma unroll
        for (int kk = 0; kk < 2; ++kk) {
            const int ko = kk * 32 + quad * 8;
            bf16x8 a[8], bh[2], bl[2];
            #pragma unroll
            for (int tm = 0; tm < 8; ++tm)
                a[tm] = *(const bf16x8*)&ps[tm * 16 + col][ko];
            #pragma unroll
            for (int tf = 0; tf < 2; ++tf) {
                int r = wx * 32 + tf * 16 + col;
                bh[tf] = *(const bf16x8*)&hsh[r][ko];
                bl[tf] = *(const bf16x8*)&hsl[r][ko];
            }
            #pragma unroll
            for (int tm = 0; tm < 8; ++tm)
                #pragma unroll
                for (int tf = 0; tf < 2; ++tf) {
                    acc[tm][tf] = __builtin_amdgcn_mfma_f32_16x16x32_bf16(a[tm], bh[tf], acc[tm][tf], 0, 0, 0);
                    acc[tm][tf] = __builtin_amdgcn_mfma_f32_16x16x32_bf16(a[tm], bl[tf], acc[tm][tf], 0, 0, 0);
                }
        }
    }

    float* op = (ks == 0) ? op0 : (ks == 1) ? op1 : (ks == 2) ? op2 : op3;
    float* ob = op + (size_t)b * 128 * 2048;
    #pragma unroll
    for (int tm = 0; tm < 8; ++tm) {
        int m = m0 + tm * 16 + quad * 4;
        #pragma unroll
        for (int tf = 0; tf < 2; ++tf) {
            int f = wx * 32 + tf * 16 + col;
            *(f32x4*)&ob[(size_t)f * 2048 + m] = acc[tm][tf];
        }
    }
}

// ---- K5: out = (op0+op1+op2+op3)_view @ Wv + bv, packed-Wv frag loads.
__global__ __launch_bounds__(512) void k_final_m3b(
    const float* __restrict__ op0, const float* __restrict__ op1,
    const float* __restrict__ op2, const float* __restrict__ op3,
    const ushort* __restrict__ wvpkh, const ushort* __restrict__ wvpkl,
    const float* __restrict__ bv, float* __restrict__ out)
{
    __shared__ ushort ash[64][136], asl[64][136];
    __shared__ float pmf[64][132];
    const int t = threadIdx.x;
    const long row0 = (long)blockIdx.x * 64;
    const int wid = t >> 6, lane = t & 63;
    const int wy = wid & 1, wx = wid >> 1;
    const int col = lane & 15, quad = lane >> 4;

    {   // stage o rows: flat sum of 4 partials, split to bf16
        const float4* s0 = (const float4*)(op0 + row0 * 128);
        const float4* s1 = (const float4*)(op1 + row0 * 128);
        const float4* s2 = (const float4*)(op2 + row0 * 128);
        const float4* s3 = (const float4*)(op3 + row0 * 128);
        #pragma unroll
        for (int i = 0; i < 4; ++i) {
            int idx = t + 512 * i;
            float4 a = s0[idx], bq = s1[idx], cq = s2[idx], dq = s3[idx];
            float v0 = ((a.x + bq.x) + cq.x) + dq.x;
            float v1 = ((a.y + bq.y) + cq.y) + dq.y;
            float v2 = ((a.z + bq.z) + cq.z) + dq.z;
            float v3 = ((a.w + bq.w) + cq.w) + dq.w;
            ushort4 h, l;
            h.x = f2bf(v0); l.x = f2bf(v0 - bf2f(h.x));
            h.y = f2bf(v1); l.y = f2bf(v1 - bf2f(h.y));
            h.z = f2bf(v2); l.z = f2bf(v2 - bf2f(h.z));
            h.w = f2bf(v3); l.w = f2bf(v3 - bf2f(h.w));
            int r = idx >> 5, c4 = idx & 31;
            *(ushort4*)&ash[r][c4 * 4] = h;
            *(ushort4*)&asl[r][c4 * 4] = l;
        }
    }
    __syncthreads();

    f32x4 acc[2][2];
    #pragma unroll
    for (int i = 0; i < 2; ++i)
        #pragma unroll
        for (int j = 0; j < 2; ++j) acc[i][j] = (f32x4){0.f, 0.f, 0.f, 0.f};

    #pragma unroll
    for (int kk = 0; kk < 4; ++kk) {
        const int ko = kk * 32 + quad * 8;
        bf16x8 ah[2], al[2], bh[2], bl[2];
        #pragma unroll
        for (int tn = 0; tn < 2; ++tn) {
            int r = wy * 32 + tn * 16 + col;
            ah[tn] = *(const bf16x8*)&ash[r][ko];
            al[tn] = *(const bf16x8*)&asl[r][ko];
        }
        #pragma unroll
        for (int tf = 0; tf < 2; ++tf) {
            size_t base = (((size_t)kk) * 8 + (wx * 2 + tf)) * 512 + (size_t)lane * 8;
            bh[tf] = *(const bf16x8*)&wvpkh[base];
            bl[tf] = *(const bf16x8*)&wvpkl[base];
        }
        #pragma unroll
        for (int tn = 0; tn < 2; ++tn)
            #pragma unroll
            for (int tf = 0; tf < 2; ++tf) {
                acc[tn][tf] = __builtin_amdgcn_mfma_f32_16x16x32_bf16(ah[tn], bh[tf], acc[tn][tf], 0, 0, 0);
                acc[tn][tf] = __builtin_amdgcn_mfma_f32_16x16x32_bf16(ah[tn], bl[tf], acc[tn][tf], 0, 0, 0);
                acc[tn][tf] = __builtin_amdgcn_mfma_f32_16x16x32_bf16(al[tn], bh[tf], acc[tn][tf], 0, 0, 0);
            }
    }

    #pragma unroll
    for (int tf = 0; tf < 2; ++tf) {
        int f = wx * 32 + tf * 16 + col;
        float bb = bv[f];
        #pragma unroll
        for (int tn = 0; tn < 2; ++tn)
            #pragma unroll
            for (int r = 0; r < 4; ++r)
                pmf[wy * 32 + tn * 16 + quad * 4 + r][f] = acc[tn][tf][r] + bb;
    }
    __syncthreads();
    #pragma unroll
    for (int i = 0; i < 4; ++i) {
        int idx = t + 512 * i;
        int r = idx >> 5, c4 = idx & 31;
        *(float4*)&out[(row0 + r) * 128 + c4 * 4] = *(const float4*)&pmf[r][c4 * 4];
    }
}

// ============================ FALLBACK (fp32, verified round 1) ============================

__global__ __launch_bounds__(256) void k_proj(
    const float* __restrict__ x,
    const float* __restrict__ W0, const float* __restrict__ b0,
    const float* __restrict__ W1, const float* __restrict__ b1,
    const float* __restrict__ W2, const float* __restrict__ b2,
    float* __restrict__ o0, float* __restrict__ o1, float* __restrict__ o2)
{
    const float* W; const float* bias; float* out;
    if (blockIdx.y == 0)      { W = W0; bias = b0; out = o0; }
    else if (blockIdx.y == 1) { W = W1; bias = b1; out = o1; }
    else                      { W = W2; bias = b2; out = o2; }

    __shared__ float xs[32][Cc];
    const int t = threadIdx.x;
    const long row0 = (long)blockIdx.x * 32;
    const float4* xg = (const float4*)(x + row0 * Cc);
    float4* xs4 = (float4*)xs;
    #pragma unroll
    for (int i = 0; i < 8; ++i) xs4[t + 256 * i] = xg[t + 256 * i];
    __syncthreads();

    const int cg = t & 31;
    const int rq = t >> 5;
    float acc[4][4] = {};
    const float4* W4 = (const float4*)W;
    for (int k4 = 0; k4 < Cc / 4; ++k4) {
        float4 av[4];
        #pragma unroll
        for (int i = 0; i < 4; ++i) av[i] = *(const float4*)&xs[4 * rq + i][k4 * 4];
        float4 wv4[4];
        #pragma unroll
        for (int kk = 0; kk < 4; ++kk) wv4[kk] = W4[(size_t)(4 * k4 + kk) * (Ff / 4) + cg];
        #pragma unroll
        for (int kk = 0; kk < 4; ++kk) {
            float4 w = wv4[kk];
            #pragma unroll
            for (int i = 0; i < 4; ++i) {
                float a = (kk == 0) ? av[i].x : (kk == 1) ? av[i].y : (kk == 2) ? av[i].z : av[i].w;
                acc[i][0] += a * w.x; acc[i][1] += a * w.y;
                acc[i][2] += a * w.z; acc[i][3] += a * w.w;
            }
        }
    }
    float4 bb = ((const float4*)bias)[cg];
    #pragma unroll
    for (int i = 0; i < 4; ++i) {
        float4 r;
        r.x = acc[i][0] + bb.x; r.y = acc[i][1] + bb.y;
        r.z = acc[i][2] + bb.z; r.w = acc[i][3] + bb.w;
        ((float4*)(out + (row0 + 4 * rq + i) * Ff))[cg] = r;
    }
}

__global__ __launch_bounds__(256) void k_stats(
    const float* __restrict__ fx, const float* __restrict__ gx,
    float* __restrict__ linv)
{
    __shared__ float fs[64][132];
    __shared__ float gs[128][132];
    const int t = threadIdx.x;
    const int n0 = blockIdx.x * 64;
    const int b = n0 / Nn;
    const float* gxb = gx + (long)b * Nn * Ff;
    {
        const float4* src = (const float4*)(fx + (long)n0 * Ff);
        #pragma unroll
        for (int i = 0; i < 8; ++i) {
            int idx = t + 256 * i;
            int r = idx >> 5, c4 = idx & 31;
            *(float4*)&fs[r][c4 * 4] = src[idx];
        }
    }
    const int ty = t >> 4;
    const int tx = t & 15;
    float lsum[4] = {0.f, 0.f, 0.f, 0.f};
    for (int mt = 0; mt < Nn / 128; ++mt) {
        __syncthreads();
        {
            const float4* src = (const float4*)(gxb + (long)mt * 128 * Ff);
            #pragma unroll
            for (int i = 0; i < 16; ++i) {
                int idx = t + 256 * i;
                int r = idx >> 5, c4 = idx & 31;
                *(float4*)&gs[r][c4 * 4] = src[idx];
            }
        }
        __syncthreads();
        float s[4][8] = {};
        for (int k4 = 0; k4 < 32; ++k4) {
            float4 a[4], g4[8];
            #pragma unroll
            for (int i = 0; i < 4; ++i) a[i] = *(const float4*)&fs[ty + 16 * i][k4 * 4];
            #pragma unroll
            for (int j = 0; j < 8; ++j) g4[j] = *(const float4*)&gs[tx + 16 * j][k4 * 4];
            #pragma unroll
            for (int i = 0; i < 4; ++i)
                #pragma unroll
                for (int j = 0; j < 8; ++j)
                    s[i][j] += a[i].x * g4[j].x + a[i].y * g4[j].y
                             + a[i].z * g4[j].z + a[i].w * g4[j].w;
        }
        #pragma unroll
        for (int i = 0; i < 4; ++i) {
            float e = 0.f;
            #pragma unroll
            for (int j = 0; j < 8; ++j) e += __expf(s[i][j]);
            lsum[i] += e;
        }
    }
    #pragma unroll
    for (int off = 1; off < 16; off <<= 1)
        #pragma unroll
        for (int i = 0; i < 4; ++i) lsum[i] += __shfl_xor(lsum[i], off);
    if (tx == 0)
        #pragma unroll
        for (int i = 0; i < 4; ++i) linv[n0 + ty + 16 * i] = 1.0f / lsum[i];
}

__global__ __launch_bounds__(256) void k_attnpv(
    const float* __restrict__ fx, const float* __restrict__ gx,
    const float* __restrict__ hx, const float* __restrict__ linv,
    float* __restrict__ o)
{
    __shared__ float gs[64][132];
    __shared__ float fs[64][132];
    __shared__ float hs[64][132];
    __shared__ float ps[64][68];
    __shared__ float li[64];
    const int t = threadIdx.x;
    const int m0g = blockIdx.x * 64;
    const int b = m0g / Nn;
    const int m0 = m0g - b * Nn;
    const float* fxb = fx + (long)b * Nn * Ff;
    const float* hxb = hx + (long)b * Nn * Ff;
    {
        const float4* src = (const float4*)(gx + (long)m0g * Ff);
        #pragma unroll
        for (int i = 0; i < 8; ++i) {
            int idx = t + 256 * i;
            int r = idx >> 5, c4 = idx & 31;
            *(float4*)&gs[r][c4 * 4] = src[idx];
        }
    }
    const int ty = t >> 4;
    const int tx = t & 15;
    float acc[4][8] = {};
    for (int nt = 0; nt < Nn / 64; ++nt) {
        __syncthreads();
        {
            const float4* srcf = (const float4*)(fxb + (long)nt * 64 * Ff);
            const float4* srch = (const float4*)(hxb + (long)nt * 64 * Ff);
            #pragma unroll
            for (int i = 0; i < 8; ++i) {
                int idx = t + 256 * i;
                int r = idx >> 5, c4 = idx & 31;
                *(float4*)&fs[r][c4 * 4] = srcf[idx];
                *(float4*)&hs[r][c4 * 4] = srch[idx];
            }
            if (t < 64) li[t] = linv[(long)b * Nn + nt * 64 + t];
        }
        __syncthreads();
        float s[4][4] = {};
        for (int k4 = 0; k4 < 32; ++k4) {
            float4 a[4], g4[4];
            #pragma unroll
            for (int i = 0; i < 4; ++i) a[i] = *(const float4*)&fs[ty + 16 * i][k4 * 4];
            #pragma unroll
            for (int j = 0; j < 4; ++j) g4[j] = *(const float4*)&gs[tx + 16 * j][k4 * 4];
            #pragma unroll
            for (int i = 0; i < 4; ++i)
                #pragma unroll
                for (int j = 0; j < 4; ++j)
                    s[i][j] += a[i].x * g4[j].x + a[i].y * g4[j].y
                             + a[i].z * g4[j].z + a[i].w * g4[j].w;
        }
        #pragma unroll
        for (int i = 0; i < 4; ++i) {
            float lv = li[ty + 16 * i];
            #pragma unroll
            for (int j = 0; j < 4; ++j)
                ps[ty + 16 * i][tx + 16 * j] = __expf(s[i][j]) * lv;
        }
        __syncthreads();
        #pragma unroll 4
        for (int n = 0; n < 64; ++n) {
            float4 h0 = *(const float4*)&hs[n][tx * 8];
            float4 h1 = *(const float4*)&hs[n][tx * 8 + 4];
            float pv[4];
            #pragma unroll
            for (int im = 0; im < 4; ++im) pv[im] = ps[n][ty + 16 * im];
            #pragma unroll
            for (int im = 0; im < 4; ++im) {
                acc[im][0] += pv[im] * h0.x; acc[im][1] += pv[im] * h0.y;
                acc[im][2] += pv[im] * h0.z; acc[im][3] += pv[im] * h0.w;
                acc[im][4] += pv[im] * h1.x; acc[im][5] += pv[im] * h1.y;
                acc[im][6] += pv[im] * h1.z; acc[im][7] += pv[im] * h1.w;
            }
        }
    }
    float* ob = o + (size_t)b * Ff * Nn;
    #pragma unroll
    for (int im = 0; im < 4; ++im) {
        int m = m0 + ty + 16 * im;
        #pragma unroll
        for (int jf = 0; jf < 8; ++jf)
            ob[(size_t)(tx * 8 + jf) * Nn + m] = acc[im][jf];
    }
}

__global__ __launch_bounds__(256) void k_final(
    const float* __restrict__ in2, const float* __restrict__ Wv,
    const float* __restrict__ bv, float* __restrict__ out)
{
    __shared__ float xs[32][132];
    const int t = threadIdx.x;
    const long row0 = (long)blockIdx.x * 32;
    {
        const float4* src = (const float4*)(in2 + row0 * Ff);
        #pragma unroll
        for (int i = 0; i < 4; ++i) {
            int idx = t + 256 * i;
            int r = idx >> 5, c4 = idx & 31;
            *(float4*)&xs[r][c4 * 4] = src[idx];
        }
    }
    __syncthreads();

    const int cg = t & 31;
    const int rq = t >> 5;
    float acc[4][4] = {};
    const float4* W4 = (const float4*)Wv;
    for (int k4 = 0; k4 < 32; ++k4) {
        float4 av[4];
        #pragma unroll
        for (int i = 0; i < 4; ++i) av[i] = *(const float4*)&xs[4 * rq + i][k4 * 4];
        float4 wv4[4];
        #pragma unroll
        for (int kk = 0; kk < 4; ++kk) wv4[kk] = W4[(size_t)(4 * k4 + kk) * 32 + cg];
        #pragma unroll
        for (int kk = 0; kk < 4; ++kk) {
            float4 w = wv4[kk];
            #pragma unroll
            for (int i = 0; i < 4; ++i) {
                float a = (kk == 0) ? av[i].x : (kk == 1) ? av[i].y : (kk == 2) ? av[i].z : av[i].w;
                acc[i][0] += a * w.x; acc[i][1] += a * w.y;
                acc[i][2] += a * w.z; acc[i][3] += a * w.w;
            }
        }
    }
    float4 bb = ((const float4*)bv)[cg];
    #pragma unroll
    for (int i = 0; i < 4; ++i) {
        float4 r;
        r.x = acc[i][0] + bb.x; r.y = acc[i][1] + bb.y;
        r.z = acc[i][2] + bb.z; r.w = acc[i][3] + bb.w;
        ((float4*)(out + (row0 + 4 * rq + i) * Ff))[cg] = r;
    }
}

// ============================ launcher ============================

extern "C" void kernel_launch(void* const* d_in, const int* in_sizes, int n_in,
                              void* d_out, int out_size, void* d_ws, size_t ws_size,
                              hipStream_t stream) {
    const float* x  = (const float*)d_in[0];
    const float* Wf = (const float*)d_in[1];
    const float* bf = (const float*)d_in[2];
    const float* Wg = (const float*)d_in[3];
    const float* bg = (const float*)d_in[4];
    const float* Wh = (const float*)d_in[5];
    const float* bh = (const float*)d_in[6];
    const float* Wv = (const float*)d_in[7];
    const float* bv = (const float*)d_in[8];
    float* out = (float*)d_out;

    const size_t sz_hxt  = (size_t)BNF * 4;
    const size_t sz_linv = (size_t)BN * 4;
    const size_t sz_bf   = (size_t)BNF * 2;
    const size_t sz_Pt   = (size_t)Bb * Nn * Nn * 2;
    const size_t sz_wt   = (size_t)3 * 128 * 256 * 2;
    const size_t sz_wv   = (size_t)128 * 128 * 2;
    const size_t need = sz_hxt + sz_linv + 8 * sz_bf + sz_Pt + 2 * sz_wt + 2 * sz_wv;

    if (ws_size >= need) {
        char* p = (char*)d_ws;
        float* hxt   = (float*)p;            p += sz_hxt;   // alive until k_pv7c
        float* linv  = (float*)p;            p += sz_linv;
        ushort* fxh  = (ushort*)p;           p += sz_bf;
        ushort* fxl  = (ushort*)p;           p += sz_bf;
        ushort* gxh  = (ushort*)p;           p += sz_bf;
        ushort* gxl  = (ushort*)p;           p += sz_bf;
        float* op0   = (float*)p;            p += 2 * sz_bf;  // former hth/htl slots
        /* spare region (2*sz_bf = BNF*4 exactly): lsum2 (128 KB) then op3
           reuses the whole spare (disjoint lifetimes). op1/op2 alias
           fxh+fxl / gxh+gxl (dead after k_score5). */
        float* lsum2 = (float*)p;
        float* op3   = (float*)p;
        float* op1   = (float*)fxh;
        float* op2   = (float*)gxh;
        p += 2 * sz_bf;
        ushort* wpkh  = (ushort*)p;          p += sz_wt;
        ushort* wpkl  = (ushort*)p;          p += sz_wt;
        ushort* wvpkh = (ushort*)p;          p += sz_wv;
        ushort* wvpkl = (ushort*)p;          p += sz_wv;
        ushort* Pt    = (ushort*)p;

        k_prepw2  <<<dim3(4, 3), 256, 0, stream>>>(Wf, Wg, Wh, wpkh, wpkl);
        k_prepwv2 <<<2, 256, 0, stream>>>(Wv, wvpkh, wvpkl);
        k_projm2b <<<BN / 64, 512, 0, stream>>>(x, wpkh, wpkl, bf, bg, bh,
                                                fxh, fxl, gxh, gxl, hxt);
        k_score5  <<<dim3(BN / 64, 2), 512, 0, stream>>>(fxh, fxl, gxh, gxl, Pt, lsum2);
        k_linv    <<<BN / 256, 256, 0, stream>>>(lsum2, linv);
        k_pv7c    <<<(BN / 128) * 4, 256, 0, stream>>>(Pt, hxt, linv, op0, op1, op2, op3);
        k_final_m3b<<<BN / 64, 512, 0, stream>>>(op0, op1, op2, op3, wvpkh, wvpkl, bv, out);
    } else {
        float* ws   = (float*)d_ws;
        float* fx   = ws;
        float* gx   = fx + BNF;
        float* hx   = gx + BNF;
        float* linv = hx + BNF;
        float* o    = linv + BN;
        k_proj  <<<dim3(BN / 32, 3), 256, 0, stream>>>(x, Wf, bf, Wg, bg, Wh, bh, fx, gx, hx);
        k_stats <<<BN / 64, 256, 0, stream>>>(fx, gx, linv);
        k_attnpv<<<BN / 64, 256, 0, stream>>>(fx, gx, hx, linv, o);
        k_final <<<BN / 32, 256, 0, stream>>>(o, Wv, bv, out);
    }
}

// Round 16
// 176.609 us; speedup vs baseline: 1.3902x; 1.0699x over previous
//
#include <hip/hip_runtime.h>
#include <hip/hip_bf16.h>

// SelfAttentionLayer1D: B=8, N=2048, C=256, F=128, fp32 in/out.
// Round-16 = round-13 VERBATIM (verified best, 178.7us). Post-13 experiments
// all regressed: R14 score diet (occupancy cap spilled persistent A-frags,
// FETCH 37->200MB), R15 pv pad/occupancy diet (45.2us vs <=43, no overlap
// gain). Locking in the best configuration.
//   k_prepw2/k_prepwv2: W in fragment-major packed order -> 1KB contiguous
//     wave B-frag loads (R7/R13 lesson: strided frag loads are
//     transaction-bound; pack small L2-hot operands).
//   k_projm2b: K staged in 2 chunks (52KB LDS, 2 blk/CU), packed W loads.
//   k_score5 : LDS-staged, reg-persistent A-frags, m-split x2 (2 blk/CU,
//     launch_bounds(512,4) -> VGPR cap 128 fits the 64 persistent VGPRs).
//   k_linv   : linv = 1/(lsum2[0]+lsum2[1]).
//   k_pv7b   : m-tile 128, split-K x4, H staged from fp32 hxt with
//     linv-scale + hi/lo split in staging (k_scaleh eliminated).
//   k_final_m3b: (op0+..+op3) @ Wv + bv, packed Wv loads.
// Fallback path (ws too small): all-fp32 implementation (round-1 verified).

constexpr int Bb = 8, Nn = 2048, Cc = 256, Ff = 128;
constexpr long BNF = (long)Bb * Nn * Ff;
constexpr long BN  = (long)Bb * Nn;

typedef __bf16 bf16x8 __attribute__((ext_vector_type(8)));
typedef float  f32x4  __attribute__((ext_vector_type(4)));

__device__ inline unsigned short f2bf(float x) {
    unsigned u = __float_as_uint(x);
    unsigned r = (u + 0x7fffu + ((u >> 16) & 1u)) >> 16;
    return (unsigned short)r;
}
__device__ inline float bf2f(unsigned short h) {
    return __uint_as_float(((unsigned)h) << 16);
}

// ============================ FAST PATH ============================

// ---- K0a: W -> fragment-packed split bf16. grid (4, 3).
__global__ __launch_bounds__(256) void k_prepw2(
    const float* __restrict__ W0, const float* __restrict__ W1,
    const float* __restrict__ W2,
    ushort* __restrict__ wpkh, ushort* __restrict__ wpkl)
{
    __shared__ float ls[64][132];
    const float* W = (blockIdx.y == 0) ? W0 : (blockIdx.y == 1) ? W1 : W2;
    const int k0 = blockIdx.x * 64;
    const int t = threadIdx.x;
    const float4* src = (const float4*)(W + (size_t)k0 * 128);
    #pragma unroll
    for (int i = 0; i < 8; ++i) {
        int idx = t + 256 * i;
        int r = idx >> 5, c4 = idx & 31;
        *(float4*)&ls[r][c4 * 4] = src[idx];
    }
    __syncthreads();
    const int lane = t & 63, grp = t >> 6;
    const int col = lane & 15, quad = lane >> 4;
    const int kc = blockIdx.x >> 1;
    const int kkb = (blockIdx.x & 1) * 2;
    #pragma unroll
    for (int g = grp; g < 16; g += 4) {
        int kk_sub = g >> 3;
        int ft = g & 7;
        int f = ft * 16 + col;
        __align__(16) ushort hb[8], lb[8];
        #pragma unroll
        for (int j = 0; j < 8; ++j) {
            float v = ls[kk_sub * 32 + quad * 8 + j][f];
            ushort h = f2bf(v);
            hb[j] = h;
            lb[j] = f2bf(v - bf2f(h));
        }
        size_t base = ((((size_t)blockIdx.y * 2 + kc) * 4 + (kkb + kk_sub)) * 8 + ft) * 512 + (size_t)lane * 8;
        *(uint4*)&wpkh[base] = *(const uint4*)&hb[0];
        *(uint4*)&wpkl[base] = *(const uint4*)&lb[0];
    }
}

// ---- K0b: Wv -> fragment-packed split bf16. grid (2).
__global__ __launch_bounds__(256) void k_prepwv2(
    const float* __restrict__ Wv,
    ushort* __restrict__ wvpkh, ushort* __restrict__ wvpkl)
{
    __shared__ float ls[64][132];
    const int k0 = blockIdx.x * 64;
    const int t = threadIdx.x;
    const float4* src = (const float4*)(Wv + (size_t)k0 * 128);
    #pragma unroll
    for (int i = 0; i < 8; ++i) {
        int idx = t + 256 * i;
        int r = idx >> 5, c4 = idx & 31;
        *(float4*)&ls[r][c4 * 4] = src[idx];
    }
    __syncthreads();
    const int lane = t & 63, grp = t >> 6;
    const int col = lane & 15, quad = lane >> 4;
    #pragma unroll
    for (int g = grp; g < 16; g += 4) {
        int kk_sub = g >> 3;
        int ft = g & 7;
        int f = ft * 16 + col;
        __align__(16) ushort hb[8], lb[8];
        #pragma unroll
        for (int j = 0; j < 8; ++j) {
            float v = ls[kk_sub * 32 + quad * 8 + j][f];
            ushort h = f2bf(v);
            hb[j] = h;
            lb[j] = f2bf(v - bf2f(h));
        }
        size_t base = (((size_t)(blockIdx.x * 2 + kk_sub)) * 8 + ft) * 512 + (size_t)lane * 8;
        *(uint4*)&wvpkh[base] = *(const uint4*)&hb[0];
        *(uint4*)&wvpkl[base] = *(const uint4*)&lb[0];
    }
}

// ---- K1: fused projections, K staged in 2 chunks, packed-W frag loads.
__global__ __launch_bounds__(512, 4) void k_projm2b(
    const float* __restrict__ x,
    const ushort* __restrict__ wpkh, const ushort* __restrict__ wpkl,
    const float* __restrict__ b0, const float* __restrict__ b1,
    const float* __restrict__ b2,
    ushort* __restrict__ fxh, ushort* __restrict__ fxl,
    ushort* __restrict__ gxh, ushort* __restrict__ gxl,
    float* __restrict__ hxt)
{
    __shared__ ushort xsh[64][136], xsl[64][136];
    __shared__ ushort pm[64][136];

    const int t = threadIdx.x;
    const long row0 = (long)blockIdx.x * 64;
    const int wid = t >> 6, lane = t & 63;
    const int wy = wid & 1, wx = wid >> 1;
    const int col = lane & 15, quad = lane >> 4;

    f32x4 acc[3][2][2];
    #pragma unroll
    for (int y = 0; y < 3; ++y)
        #pragma unroll
        for (int i = 0; i < 2; ++i)
            #pragma unroll
            for (int j = 0; j < 2; ++j) acc[y][i][j] = (f32x4){0.f, 0.f, 0.f, 0.f};

    for (int kc = 0; kc < 2; ++kc) {
        if (kc) __syncthreads();
        {
            #pragma unroll
            for (int i = 0; i < 4; ++i) {
                int idx = t + 512 * i;
                int r = idx >> 5, c4 = idx & 31;
                float4 v = *(const float4*)&x[(row0 + r) * 256 + kc * 128 + c4 * 4];
                ushort4 h, l;
                h.x = f2bf(v.x); l.x = f2bf(v.x - bf2f(h.x));
                h.y = f2bf(v.y); l.y = f2bf(v.y - bf2f(h.y));
                h.z = f2bf(v.z); l.z = f2bf(v.z - bf2f(h.z));
                h.w = f2bf(v.w); l.w = f2bf(v.w - bf2f(h.w));
                *(ushort4*)&xsh[r][c4 * 4] = h;
                *(ushort4*)&xsl[r][c4 * 4] = l;
            }
        }
        __syncthreads();

        #pragma unroll
        for (int y = 0; y < 3; ++y) {
            #pragma unroll
            for (int kk = 0; kk < 4; ++kk) {
                const int ko = kk * 32 + quad * 8;
                bf16x8 ah[2], al[2], bh[2], bl[2];
                #pragma unroll
                for (int tn = 0; tn < 2; ++tn) {
                    int r = wy * 32 + tn * 16 + col;
                    ah[tn] = *(const bf16x8*)&xsh[r][ko];
                    al[tn] = *(const bf16x8*)&xsl[r][ko];
                }
                #pragma unroll
                for (int tf = 0; tf < 2; ++tf) {
                    size_t base = ((((size_t)y * 2 + kc) * 4 + kk) * 8 + (wx * 2 + tf)) * 512 + (size_t)lane * 8;
                    bh[tf] = *(const bf16x8*)&wpkh[base];
                    bl[tf] = *(const bf16x8*)&wpkl[base];
                }
                #pragma unroll
                for (int tn = 0; tn < 2; ++tn)
                    #pragma unroll
                    for (int tf = 0; tf < 2; ++tf) {
                        acc[y][tn][tf] = __builtin_amdgcn_mfma_f32_16x16x32_bf16(ah[tn], bh[tf], acc[y][tn][tf], 0, 0, 0);
                        acc[y][tn][tf] = __builtin_amdgcn_mfma_f32_16x16x32_bf16(ah[tn], bl[tf], acc[y][tn][tf], 0, 0, 0);
                        acc[y][tn][tf] = __builtin_amdgcn_mfma_f32_16x16x32_bf16(al[tn], bh[tf], acc[y][tn][tf], 0, 0, 0);
                    }
            }
        }
    }

    #pragma unroll
    for (int y = 0; y < 3; ++y) {
        const float* bias = (y == 0) ? b0 : (y == 1) ? b1 : b2;
        float v[2][2][4];
        #pragma unroll
        for (int tf = 0; tf < 2; ++tf) {
            float bb = bias[wx * 32 + tf * 16 + col];
            #pragma unroll
            for (int tn = 0; tn < 2; ++tn)
                #pragma unroll
                for (int r = 0; r < 4; ++r) v[tn][tf][r] = acc[y][tn][tf][r] + bb;
        }

        if (y == 2) {
            float* ob = hxt + (row0 >> 11) * (size_t)128 * 2048;
            int n0 = (int)(row0 & 2047);
            #pragma unroll
            for (int tn = 0; tn < 2; ++tn) {
                int n = n0 + wy * 32 + tn * 16 + quad * 4;
                #pragma unroll
                for (int tf = 0; tf < 2; ++tf) {
                    int f = wx * 32 + tf * 16 + col;
                    f32x4 vv = {v[tn][tf][0], v[tn][tf][1], v[tn][tf][2], v[tn][tf][3]};
                    *(f32x4*)&ob[(size_t)f * 2048 + n] = vv;
                }
            }
        } else {
            ushort* oh = (y == 0) ? fxh : gxh;
            ushort* ol = (y == 0) ? fxl : gxl;
            if (y == 0) __syncthreads();
            #pragma unroll
            for (int tn = 0; tn < 2; ++tn)
                #pragma unroll
                for (int tf = 0; tf < 2; ++tf)
                    #pragma unroll
                    for (int r = 0; r < 4; ++r)
                        pm[wy * 32 + tn * 16 + quad * 4 + r][wx * 32 + tf * 16 + col] = f2bf(v[tn][tf][r]);
            __syncthreads();
            #pragma unroll
            for (int i = 0; i < 2; ++i) {
                int idx = t + 512 * i;
                int r = idx >> 4, c = idx & 15;
                *(uint4*)&oh[(row0 + r) * 128 + c * 8] = *(const uint4*)&pm[r][c * 8];
            }
            __syncthreads();
            #pragma unroll
            for (int tn = 0; tn < 2; ++tn)
                #pragma unroll
                for (int tf = 0; tf < 2; ++tf)
                    #pragma unroll
                    for (int r = 0; r < 4; ++r) {
                        float hv = bf2f(f2bf(v[tn][tf][r]));
                        pm[wy * 32 + tn * 16 + quad * 4 + r][wx * 32 + tf * 16 + col] = f2bf(v[tn][tf][r] - hv);
                    }
            __syncthreads();
            #pragma unroll
            for (int i = 0; i < 2; ++i) {
                int idx = t + 512 * i;
                int r = idx >> 4, c = idx & 15;
                *(uint4*)&ol[(row0 + r) * 128 + c * 8] = *(const uint4*)&pm[r][c * 8];
            }
            __syncthreads();
        }
    }
}

// ---- K2: score, LDS-staged, m-split x2 (round-8/13 verified). grid (BN/64, 2).
__global__ __launch_bounds__(512, 4) void k_score5(
    const ushort* __restrict__ fxh, const ushort* __restrict__ fxl,
    const ushort* __restrict__ gxh, const ushort* __restrict__ gxl,
    ushort* __restrict__ Pt, float* __restrict__ lsum2)
{
    __shared__ ushort gsh[64][136], gsl[64][136];       // 17.4 KB each
    __shared__ __align__(16) ushort fsbuf[2 * 64 * 136]; // 34.8 KB, reused as pm
    __shared__ float lsum[64];
    ushort* fsh = fsbuf;
    ushort* fsl = fsbuf + 64 * 136;
    ushort* pm  = fsbuf;            // [64][72] after A-frag load

    const int t = threadIdx.x;
    const int n0g = blockIdx.x * 64;
    const int ms = blockIdx.y;               // m-split 0..1
    const int b = n0g >> 11;
    const int n0 = n0g & 2047;
    const int wid = t >> 6, lane = t & 63;
    const int wy = wid & 1, wx = wid >> 1;   // wy: n half(32), wx: m quarter(16)
    const int col = lane & 15, quad = lane >> 4;

    {   // stage fx tiles, then hoist A-frags to registers
        const uint4* sh = (const uint4*)(fxh + (size_t)n0g * 128);
        const uint4* sl = (const uint4*)(fxl + (size_t)n0g * 128);
        #pragma unroll
        for (int i = 0; i < 2; ++i) {
            int idx = t + 512 * i;
            int r = idx >> 4, c = idx & 15;
            *(uint4*)&fsh[r * 136 + c * 8] = sh[idx];
            *(uint4*)&fsl[r * 136 + c * 8] = sl[idx];
        }
        if (t < 64) lsum[t] = 0.f;
    }
    __syncthreads();

    bf16x8 Ah[4][2], Al[4][2];
    #pragma unroll
    for (int kk = 0; kk < 4; ++kk) {
        const int ko = kk * 32 + quad * 8;
        #pragma unroll
        for (int tn = 0; tn < 2; ++tn) {
            int r = wy * 32 + tn * 16 + col;
            Ah[kk][tn] = *(const bf16x8*)&fsh[r * 136 + ko];
            Al[kk][tn] = *(const bf16x8*)&fsl[r * 136 + ko];
        }
    }

    float rs[2][4] = {};
    const ushort* gbh = gxh + (size_t)b * 2048 * 128;
    const ushort* gbl = gxl + (size_t)b * 2048 * 128;
    ushort* Pb = Pt + (size_t)b * 2048 * 2048;

    for (int mt = 0; mt < 16; ++mt) {
        const int m0 = ms * 1024 + mt * 64;
        __syncthreads();   // fs/pm reads done
        {   // gx m-tile 64 x 128, hi+lo (coalesced)
            const uint4* sh = (const uint4*)(gbh + (size_t)m0 * 128);
            const uint4* sl = (const uint4*)(gbl + (size_t)m0 * 128);
            #pragma unroll
            for (int i = 0; i < 2; ++i) {
                int idx = t + 512 * i;
                int r = idx >> 4, c = idx & 15;
                *(uint4*)&gsh[r][c * 8] = sh[idx];
                *(uint4*)&gsl[r][c * 8] = sl[idx];
            }
        }
        __syncthreads();

        f32x4 acc[2];
        acc[0] = (f32x4){0.f, 0.f, 0.f, 0.f};
        acc[1] = (f32x4){0.f, 0.f, 0.f, 0.f};

        #pragma unroll
        for (int kk = 0; kk < 4; ++kk) {
            const int ko = kk * 32 + quad * 8;
            int r = wx * 16 + col;
            bf16x8 bh = *(const bf16x8*)&gsh[r][ko];
            bf16x8 bl = *(const bf16x8*)&gsl[r][ko];
            #pragma unroll
            for (int tn = 0; tn < 2; ++tn) {
                acc[tn] = __builtin_amdgcn_mfma_f32_16x16x32_bf16(Ah[kk][tn], bh, acc[tn], 0, 0, 0);
                acc[tn] = __builtin_amdgcn_mfma_f32_16x16x32_bf16(Ah[kk][tn], bl, acc[tn], 0, 0, 0);
                acc[tn] = __builtin_amdgcn_mfma_f32_16x16x32_bf16(Al[kk][tn], bh, acc[tn], 0, 0, 0);
            }
        }

        // exp, rowsum partials, P-tile [m][n] into pm
        #pragma unroll
        for (int tn = 0; tn < 2; ++tn) {
            float e0 = __expf(acc[tn][0]);
            float e1 = __expf(acc[tn][1]);
            float e2 = __expf(acc[tn][2]);
            float e3 = __expf(acc[tn][3]);
            rs[tn][0] += e0; rs[tn][1] += e1; rs[tn][2] += e2; rs[tn][3] += e3;
            ushort4 pk;
            pk.x = f2bf(e0); pk.y = f2bf(e1); pk.z = f2bf(e2); pk.w = f2bf(e3);
            int ml = wx * 16 + col;
            int nl = wy * 32 + tn * 16 + quad * 4;
            *(ushort4*)&pm[ml * 72 + nl] = pk;
        }
        __syncthreads();
        {   // coalesced P^T store: 64 rows x 64 n
            int r = t >> 3, c = t & 7;
            *(uint4*)&Pb[(size_t)(m0 + r) * 2048 + n0 + c * 8] = *(const uint4*)&pm[r * 72 + c * 8];
        }
    }

    #pragma unroll
    for (int off = 1; off < 16; off <<= 1)
        #pragma unroll
        for (int tn = 0; tn < 2; ++tn)
            #pragma unroll
            for (int r = 0; r < 4; ++r) rs[tn][r] += __shfl_xor(rs[tn][r], off);
    if (col == 0) {
        #pragma unroll
        for (int tn = 0; tn < 2; ++tn)
            #pragma unroll
            for (int r = 0; r < 4; ++r)
                atomicAdd(&lsum[wy * 32 + tn * 16 + quad * 4 + r], rs[tn][r]);
    }
    __syncthreads();
    if (t < 64) lsum2[(size_t)ms * BN + n0g + t] = lsum[t];
}

// ---- K3: linv = 1/(lsum2[0]+lsum2[1]). grid BN/256 = 64 blocks.
__global__ __launch_bounds__(256) void k_linv(
    const float* __restrict__ lsum2, float* __restrict__ linv)
{
    const long i = (long)blockIdx.x * 256 + threadIdx.x;
    linv[i] = 1.0f / (lsum2[i] + lsum2[BN + i]);
}

// ---- K4: PV, m-tile 128, split-K x4; H staged from fp32 hxt with
// linv-scale + hi/lo split IN the staging loop. grid (BN/128)*4 = 512, 256 thr.
__global__ __launch_bounds__(256, 2) void k_pv7b(
    const ushort* __restrict__ Pt,
    const float* __restrict__ hxt, const float* __restrict__ linv,
    float* __restrict__ op0, float* __restrict__ op1,
    float* __restrict__ op2, float* __restrict__ op3)
{
    __shared__ ushort ps[128][72];                 // 18.4 KB
    __shared__ ushort hsh[128][72], hsl[128][72];  // 18.4 KB each
    const int t = threadIdx.x;
    const int ks = blockIdx.x & 3;
    const int m0g = (blockIdx.x >> 2) * 128;
    const int b = m0g >> 11, m0 = m0g & 2047;
    const int wx = t >> 6;                 // f quarter(32)
    const int lane = t & 63;
    const int col = lane & 15, quad = lane >> 4;
    const int nbase = ks * 512;

    const ushort* Pb = Pt + ((size_t)b * 2048 + m0) * 2048 + nbase;
    const float* Hx = hxt + (size_t)b * 128 * 2048 + nbase;
    const float* Lv = linv + (size_t)b * 2048 + nbase;

    f32x4 acc[8][2];
    #pragma unroll
    for (int i = 0; i < 8; ++i)
        #pragma unroll
        for (int j = 0; j < 2; ++j) acc[i][j] = (f32x4){0.f, 0.f, 0.f, 0.f};

    for (int nt = 0; nt < 8; ++nt) {
        __syncthreads();   // prev LDS reads done
        {   // stage P (128m x 64n) and H = hxt*linv split (128f x 64n)
            #pragma unroll
            for (int i = 0; i < 4; ++i) {
                int idx = t + 256 * i;
                int r = idx >> 3, c = idx & 7;
                size_t g = (size_t)r * 2048 + nt * 64 + c * 8;
                *(uint4*)&ps[r][c * 8] = *(const uint4*)&Pb[g];
                float4 h0 = *(const float4*)&Hx[g];
                float4 h1 = *(const float4*)&Hx[g + 4];
                float4 l0 = *(const float4*)&Lv[nt * 64 + c * 8];
                float4 l1 = *(const float4*)&Lv[nt * 64 + c * 8 + 4];
                float w[8] = {h0.x * l0.x, h0.y * l0.y, h0.z * l0.z, h0.w * l0.w,
                              h1.x * l1.x, h1.y * l1.y, h1.z * l1.z, h1.w * l1.w};
                __align__(16) ushort hb[8], lb[8];
                #pragma unroll
                for (int j = 0; j < 8; ++j) {
                    ushort h = f2bf(w[j]);
                    hb[j] = h;
                    lb[j] = f2bf(w[j] - bf2f(h));
                }
                *(uint4*)&hsh[r][c * 8] = *(const uint4*)&hb[0];
                *(uint4*)&hsl[r][c * 8] = *(const uint4*)&lb[0];
            }
        }
        __syncthreads();

        #pragma unroll
        for (int kk = 0; kk < 2; ++kk) {
            const int ko = kk * 32 + quad * 8;
            bf16x8 a[8], bh[2], bl[2];
            #pragma unroll
            for (int tm = 0; tm < 8; ++tm)
                a[tm] = *(const bf16x8*)&ps[tm * 16 + col][ko];
            #pragma unroll
            for (int tf = 0; tf < 2; ++tf) {
                int r = wx * 32 + tf * 16 + col;
                bh[tf] = *(const bf16x8*)&hsh[r][ko];
                bl[tf] = *(const bf16x8*)&hsl[r][ko];
            }
            #pragma unroll
            for (int tm = 0; tm < 8; ++tm)
                #pragma unroll
                for (int tf = 0; tf < 2; ++tf) {
                    acc[tm][tf] = __builtin_amdgcn_mfma_f32_16x16x32_bf16(a[tm], bh[tf], acc[tm][tf], 0, 0, 0);
                    acc[tm][tf] = __builtin_amdgcn_mfma_f32_16x16x32_bf16(a[tm], bl[tf], acc[tm][tf], 0, 0, 0);
                }
        }
    }

    float* op = (ks == 0) ? op0 : (ks == 1) ? op1 : (ks == 2) ? op2 : op3;
    float* ob = op + (size_t)b * 128 * 2048;
    #pragma unroll
    for (int tm = 0; tm < 8; ++tm) {
        int m = m0 + tm * 16 + quad * 4;
        #pragma unroll
        for (int tf = 0; tf < 2; ++tf) {
            int f = wx * 32 + tf * 16 + col;
            *(f32x4*)&ob[(size_t)f * 2048 + m] = acc[tm][tf];
        }
    }
}

// ---- K5: out = (op0+op1+op2+op3)_view @ Wv + bv, packed-Wv frag loads.
__global__ __launch_bounds__(512) void k_final_m3b(
    const float* __restrict__ op0, const float* __restrict__ op1,
    const float* __restrict__ op2, const float* __restrict__ op3,
    const ushort* __restrict__ wvpkh, const ushort* __restrict__ wvpkl,
    const float* __restrict__ bv, float* __restrict__ out)
{
    __shared__ ushort ash[64][136], asl[64][136];
    __shared__ float pmf[64][132];
    const int t = threadIdx.x;
    const long row0 = (long)blockIdx.x * 64;
    const int wid = t >> 6, lane = t & 63;
    const int wy = wid & 1, wx = wid >> 1;
    const int col = lane & 15, quad = lane >> 4;

    {   // stage o rows: flat sum of 4 partials, split to bf16
        const float4* s0 = (const float4*)(op0 + row0 * 128);
        const float4* s1 = (const float4*)(op1 + row0 * 128);
        const float4* s2 = (const float4*)(op2 + row0 * 128);
        const float4* s3 = (const float4*)(op3 + row0 * 128);
        #pragma unroll
        for (int i = 0; i < 4; ++i) {
            int idx = t + 512 * i;
            float4 a = s0[idx], bq = s1[idx], cq = s2[idx], dq = s3[idx];
            float v0 = ((a.x + bq.x) + cq.x) + dq.x;
            float v1 = ((a.y + bq.y) + cq.y) + dq.y;
            float v2 = ((a.z + bq.z) + cq.z) + dq.z;
            float v3 = ((a.w + bq.w) + cq.w) + dq.w;
            ushort4 h, l;
            h.x = f2bf(v0); l.x = f2bf(v0 - bf2f(h.x));
            h.y = f2bf(v1); l.y = f2bf(v1 - bf2f(h.y));
            h.z = f2bf(v2); l.z = f2bf(v2 - bf2f(h.z));
            h.w = f2bf(v3); l.w = f2bf(v3 - bf2f(h.w));
            int r = idx >> 5, c4 = idx & 31;
            *(ushort4*)&ash[r][c4 * 4] = h;
            *(ushort4*)&asl[r][c4 * 4] = l;
        }
    }
    __syncthreads();

    f32x4 acc[2][2];
    #pragma unroll
    for (int i = 0; i < 2; ++i)
        #pragma unroll
        for (int j = 0; j < 2; ++j) acc[i][j] = (f32x4){0.f, 0.f, 0.f, 0.f};

    #pragma unroll
    for (int kk = 0; kk < 4; ++kk) {
        const int ko = kk * 32 + quad * 8;
        bf16x8 ah[2], al[2], bh[2], bl[2];
        #pragma unroll
        for (int tn = 0; tn < 2; ++tn) {
            int r = wy * 32 + tn * 16 + col;
            ah[tn] = *(const bf16x8*)&ash[r][ko];
            al[tn] = *(const bf16x8*)&asl[r][ko];
        }
        #pragma unroll
        for (int tf = 0; tf < 2; ++tf) {
            size_t base = (((size_t)kk) * 8 + (wx * 2 + tf)) * 512 + (size_t)lane * 8;
            bh[tf] = *(const bf16x8*)&wvpkh[base];
            bl[tf] = *(const bf16x8*)&wvpkl[base];
        }
        #pragma unroll
        for (int tn = 0; tn < 2; ++tn)
            #pragma unroll
            for (int tf = 0; tf < 2; ++tf) {
                acc[tn][tf] = __builtin_amdgcn_mfma_f32_16x16x32_bf16(ah[tn], bh[tf], acc[tn][tf], 0, 0, 0);
                acc[tn][tf] = __builtin_amdgcn_mfma_f32_16x16x32_bf16(ah[tn], bl[tf], acc[tn][tf], 0, 0, 0);
                acc[tn][tf] = __builtin_amdgcn_mfma_f32_16x16x32_bf16(al[tn], bh[tf], acc[tn][tf], 0, 0, 0);
            }
    }

    #pragma unroll
    for (int tf = 0; tf < 2; ++tf) {
        int f = wx * 32 + tf * 16 + col;
        float bb = bv[f];
        #pragma unroll
        for (int tn = 0; tn < 2; ++tn)
            #pragma unroll
            for (int r = 0; r < 4; ++r)
                pmf[wy * 32 + tn * 16 + quad * 4 + r][f] = acc[tn][tf][r] + bb;
    }
    __syncthreads();
    #pragma unroll
    for (int i = 0; i < 4; ++i) {
        int idx = t + 512 * i;
        int r = idx >> 5, c4 = idx & 31;
        *(float4*)&out[(row0 + r) * 128 + c4 * 4] = *(const float4*)&pmf[r][c4 * 4];
    }
}

// ============================ FALLBACK (fp32, verified round 1) ============================

__global__ __launch_bounds__(256) void k_proj(
    const float* __restrict__ x,
    const float* __restrict__ W0, const float* __restrict__ b0,
    const float* __restrict__ W1, const float* __restrict__ b1,
    const float* __restrict__ W2, const float* __restrict__ b2,
    float* __restrict__ o0, float* __restrict__ o1, float* __restrict__ o2)
{
    const float* W; const float* bias; float* out;
    if (blockIdx.y == 0)      { W = W0; bias = b0; out = o0; }
    else if (blockIdx.y == 1) { W = W1; bias = b1; out = o1; }
    else                      { W = W2; bias = b2; out = o2; }

    __shared__ float xs[32][Cc];
    const int t = threadIdx.x;
    const long row0 = (long)blockIdx.x * 32;
    const float4* xg = (const float4*)(x + row0 * Cc);
    float4* xs4 = (float4*)xs;
    #pragma unroll
    for (int i = 0; i < 8; ++i) xs4[t + 256 * i] = xg[t + 256 * i];
    __syncthreads();

    const int cg = t & 31;
    const int rq = t >> 5;
    float acc[4][4] = {};
    const float4* W4 = (const float4*)W;
    for (int k4 = 0; k4 < Cc / 4; ++k4) {
        float4 av[4];
        #pragma unroll
        for (int i = 0; i < 4; ++i) av[i] = *(const float4*)&xs[4 * rq + i][k4 * 4];
        float4 wv4[4];
        #pragma unroll
        for (int kk = 0; kk < 4; ++kk) wv4[kk] = W4[(size_t)(4 * k4 + kk) * (Ff / 4) + cg];
        #pragma unroll
        for (int kk = 0; kk < 4; ++kk) {
            float4 w = wv4[kk];
            #pragma unroll
            for (int i = 0; i < 4; ++i) {
                float a = (kk == 0) ? av[i].x : (kk == 1) ? av[i].y : (kk == 2) ? av[i].z : av[i].w;
                acc[i][0] += a * w.x; acc[i][1] += a * w.y;
                acc[i][2] += a * w.z; acc[i][3] += a * w.w;
            }
        }
    }
    float4 bb = ((const float4*)bias)[cg];
    #pragma unroll
    for (int i = 0; i < 4; ++i) {
        float4 r;
        r.x = acc[i][0] + bb.x; r.y = acc[i][1] + bb.y;
        r.z = acc[i][2] + bb.z; r.w = acc[i][3] + bb.w;
        ((float4*)(out + (row0 + 4 * rq + i) * Ff))[cg] = r;
    }
}

__global__ __launch_bounds__(256) void k_stats(
    const float* __restrict__ fx, const float* __restrict__ gx,
    float* __restrict__ linv)
{
    __shared__ float fs[64][132];
    __shared__ float gs[128][132];
    const int t = threadIdx.x;
    const int n0 = blockIdx.x * 64;
    const int b = n0 / Nn;
    const float* gxb = gx + (long)b * Nn * Ff;
    {
        const float4* src = (const float4*)(fx + (long)n0 * Ff);
        #pragma unroll
        for (int i = 0; i < 8; ++i) {
            int idx = t + 256 * i;
            int r = idx >> 5, c4 = idx & 31;
            *(float4*)&fs[r][c4 * 4] = src[idx];
        }
    }
    const int ty = t >> 4;
    const int tx = t & 15;
    float lsum[4] = {0.f, 0.f, 0.f, 0.f};
    for (int mt = 0; mt < Nn / 128; ++mt) {
        __syncthreads();
        {
            const float4* src = (const float4*)(gxb + (long)mt * 128 * Ff);
            #pragma unroll
            for (int i = 0; i < 16; ++i) {
                int idx = t + 256 * i;
                int r = idx >> 5, c4 = idx & 31;
                *(float4*)&gs[r][c4 * 4] = src[idx];
            }
        }
        __syncthreads();
        float s[4][8] = {};
        for (int k4 = 0; k4 < 32; ++k4) {
            float4 a[4], g4[8];
            #pragma unroll
            for (int i = 0; i < 4; ++i) a[i] = *(const float4*)&fs[ty + 16 * i][k4 * 4];
            #pragma unroll
            for (int j = 0; j < 8; ++j) g4[j] = *(const float4*)&gs[tx + 16 * j][k4 * 4];
            #pragma unroll
            for (int i = 0; i < 4; ++i)
                #pragma unroll
                for (int j = 0; j < 8; ++j)
                    s[i][j] += a[i].x * g4[j].x + a[i].y * g4[j].y
                             + a[i].z * g4[j].z + a[i].w * g4[j].w;
        }
        #pragma unroll
        for (int i = 0; i < 4; ++i) {
            float e = 0.f;
            #pragma unroll
            for (int j = 0; j < 8; ++j) e += __expf(s[i][j]);
            lsum[i] += e;
        }
    }
    #pragma unroll
    for (int off = 1; off < 16; off <<= 1)
        #pragma unroll
        for (int i = 0; i < 4; ++i) lsum[i] += __shfl_xor(lsum[i], off);
    if (tx == 0)
        #pragma unroll
        for (int i = 0; i < 4; ++i) linv[n0 + ty + 16 * i] = 1.0f / lsum[i];
}

__global__ __launch_bounds__(256) void k_attnpv(
    const float* __restrict__ fx, const float* __restrict__ gx,
    const float* __restrict__ hx, const float* __restrict__ linv,
    float* __restrict__ o)
{
    __shared__ float gs[64][132];
    __shared__ float fs[64][132];
    __shared__ float hs[64][132];
    __shared__ float ps[64][68];
    __shared__ float li[64];
    const int t = threadIdx.x;
    const int m0g = blockIdx.x * 64;
    const int b = m0g / Nn;
    const int m0 = m0g - b * Nn;
    const float* fxb = fx + (long)b * Nn * Ff;
    const float* hxb = hx + (long)b * Nn * Ff;
    {
        const float4* src = (const float4*)(gx + (long)m0g * Ff);
        #pragma unroll
        for (int i = 0; i < 8; ++i) {
            int idx = t + 256 * i;
            int r = idx >> 5, c4 = idx & 31;
            *(float4*)&gs[r][c4 * 4] = src[idx];
        }
    }
    const int ty = t >> 4;
    const int tx = t & 15;
    float acc[4][8] = {};
    for (int nt = 0; nt < Nn / 64; ++nt) {
        __syncthreads();
        {
            const float4* srcf = (const float4*)(fxb + (long)nt * 64 * Ff);
            const float4* srch = (const float4*)(hxb + (long)nt * 64 * Ff);
            #pragma unroll
            for (int i = 0; i < 8; ++i) {
                int idx = t + 256 * i;
                int r = idx >> 5, c4 = idx & 31;
                *(float4*)&fs[r][c4 * 4] = srcf[idx];
                *(float4*)&hs[r][c4 * 4] = srch[idx];
            }
            if (t < 64) li[t] = linv[(long)b * Nn + nt * 64 + t];
        }
        __syncthreads();
        float s[4][4] = {};
        for (int k4 = 0; k4 < 32; ++k4) {
            float4 a[4], g4[4];
            #pragma unroll
            for (int i = 0; i < 4; ++i) a[i] = *(const float4*)&fs[ty + 16 * i][k4 * 4];
            #pragma unroll
            for (int j = 0; j < 4; ++j) g4[j] = *(const float4*)&gs[tx + 16 * j][k4 * 4];
            #pragma unroll
            for (int i = 0; i < 4; ++i)
                #pragma unroll
                for (int j = 0; j < 4; ++j)
                    s[i][j] += a[i].x * g4[j].x + a[i].y * g4[j].y
                             + a[i].z * g4[j].z + a[i].w * g4[j].w;
        }
        #pragma unroll
        for (int i = 0; i < 4; ++i) {
            float lv = li[ty + 16 * i];
            #pragma unroll
            for (int j = 0; j < 4; ++j)
                ps[ty + 16 * i][tx + 16 * j] = __expf(s[i][j]) * lv;
        }
        __syncthreads();
        #pragma unroll 4
        for (int n = 0; n < 64; ++n) {
            float4 h0 = *(const float4*)&hs[n][tx * 8];
            float4 h1 = *(const float4*)&hs[n][tx * 8 + 4];
            float pv[4];
            #pragma unroll
            for (int im = 0; im < 4; ++im) pv[im] = ps[n][ty + 16 * im];
            #pragma unroll
            for (int im = 0; im < 4; ++im) {
                acc[im][0] += pv[im] * h0.x; acc[im][1] += pv[im] * h0.y;
                acc[im][2] += pv[im] * h0.z; acc[im][3] += pv[im] * h0.w;
                acc[im][4] += pv[im] * h1.x; acc[im][5] += pv[im] * h1.y;
                acc[im][6] += pv[im] * h1.z; acc[im][7] += pv[im] * h1.w;
            }
        }
    }
    float* ob = o + (size_t)b * Ff * Nn;
    #pragma unroll
    for (int im = 0; im < 4; ++im) {
        int m = m0 + ty + 16 * im;
        #pragma unroll
        for (int jf = 0; jf < 8; ++jf)
            ob[(size_t)(tx * 8 + jf) * Nn + m] = acc[im][jf];
    }
}

__global__ __launch_bounds__(256) void k_final(
    const float* __restrict__ in2, const float* __restrict__ Wv,
    const float* __restrict__ bv, float* __restrict__ out)
{
    __shared__ float xs[32][132];
    const int t = threadIdx.x;
    const long row0 = (long)blockIdx.x * 32;
    {
        const float4* src = (const float4*)(in2 + row0 * Ff);
        #pragma unroll
        for (int i = 0; i < 4; ++i) {
            int idx = t + 256 * i;
            int r = idx >> 5, c4 = idx & 31;
            *(float4*)&xs[r][c4 * 4] = src[idx];
        }
    }
    __syncthreads();

    const int cg = t & 31;
    const int rq = t >> 5;
    float acc[4][4] = {};
    const float4* W4 = (const float4*)Wv;
    for (int k4 = 0; k4 < 32; ++k4) {
        float4 av[4];
        #pragma unroll
        for (int i = 0; i < 4; ++i) av[i] = *(const float4*)&xs[4 * rq + i][k4 * 4];
        float4 wv4[4];
        #pragma unroll
        for (int kk = 0; kk < 4; ++kk) wv4[kk] = W4[(size_t)(4 * k4 + kk) * 32 + cg];
        #pragma unroll
        for (int kk = 0; kk < 4; ++kk) {
            float4 w = wv4[kk];
            #pragma unroll
            for (int i = 0; i < 4; ++i) {
                float a = (kk == 0) ? av[i].x : (kk == 1) ? av[i].y : (kk == 2) ? av[i].z : av[i].w;
                acc[i][0] += a * w.x; acc[i][1] += a * w.y;
                acc[i][2] += a * w.z; acc[i][3] += a * w.w;
            }
        }
    }
    float4 bb = ((const float4*)bv)[cg];
    #pragma unroll
    for (int i = 0; i < 4; ++i) {
        float4 r;
        r.x = acc[i][0] + bb.x; r.y = acc[i][1] + bb.y;
        r.z = acc[i][2] + bb.z; r.w = acc[i][3] + bb.w;
        ((float4*)(out + (row0 + 4 * rq + i) * Ff))[cg] = r;
    }
}

// ============================ launcher ============================

extern "C" void kernel_launch(void* const* d_in, const int* in_sizes, int n_in,
                              void* d_out, int out_size, void* d_ws, size_t ws_size,
                              hipStream_t stream) {
    const float* x  = (const float*)d_in[0];
    const float* Wf = (const float*)d_in[1];
    const float* bf = (const float*)d_in[2];
    const float* Wg = (const float*)d_in[3];
    const float* bg = (const float*)d_in[4];
    const float* Wh = (const float*)d_in[5];
    const float* bh = (const float*)d_in[6];
    const float* Wv = (const float*)d_in[7];
    const float* bv = (const float*)d_in[8];
    float* out = (float*)d_out;

    const size_t sz_hxt  = (size_t)BNF * 4;
    const size_t sz_linv = (size_t)BN * 4;
    const size_t sz_bf   = (size_t)BNF * 2;
    const size_t sz_Pt   = (size_t)Bb * Nn * Nn * 2;
    const size_t sz_wt   = (size_t)3 * 128 * 256 * 2;
    const size_t sz_wv   = (size_t)128 * 128 * 2;
    const size_t need = sz_hxt + sz_linv + 8 * sz_bf + sz_Pt + 2 * sz_wt + 2 * sz_wv;

    if (ws_size >= need) {
        char* p = (char*)d_ws;
        float* hxt   = (float*)p;            p += sz_hxt;   // alive until k_pv7b
        float* linv  = (float*)p;            p += sz_linv;
        ushort* fxh  = (ushort*)p;           p += sz_bf;
        ushort* fxl  = (ushort*)p;           p += sz_bf;
        ushort* gxh  = (ushort*)p;           p += sz_bf;
        ushort* gxl  = (ushort*)p;           p += sz_bf;
        float* op0   = (float*)p;            p += 2 * sz_bf;  // former hth/htl slots
        /* spare region (2*sz_bf = BNF*4 exactly): lsum2 (128 KB) then op3
           reuses the whole spare (disjoint lifetimes). op1/op2 alias
           fxh+fxl / gxh+gxl (dead after k_score5). */
        float* lsum2 = (float*)p;
        float* op3   = (float*)p;
        float* op1   = (float*)fxh;
        float* op2   = (float*)gxh;
        p += 2 * sz_bf;
        ushort* wpkh  = (ushort*)p;          p += sz_wt;
        ushort* wpkl  = (ushort*)p;          p += sz_wt;
        ushort* wvpkh = (ushort*)p;          p += sz_wv;
        ushort* wvpkl = (ushort*)p;          p += sz_wv;
        ushort* Pt    = (ushort*)p;

        k_prepw2  <<<dim3(4, 3), 256, 0, stream>>>(Wf, Wg, Wh, wpkh, wpkl);
        k_prepwv2 <<<2, 256, 0, stream>>>(Wv, wvpkh, wvpkl);
        k_projm2b <<<BN / 64, 512, 0, stream>>>(x, wpkh, wpkl, bf, bg, bh,
                                                fxh, fxl, gxh, gxl, hxt);
        k_score5  <<<dim3(BN / 64, 2), 512, 0, stream>>>(fxh, fxl, gxh, gxl, Pt, lsum2);
        k_linv    <<<BN / 256, 256, 0, stream>>>(lsum2, linv);
        k_pv7b    <<<(BN / 128) * 4, 256, 0, stream>>>(Pt, hxt, linv, op0, op1, op2, op3);
        k_final_m3b<<<BN / 64, 512, 0, stream>>>(op0, op1, op2, op3, wvpkh, wvpkl, bv, out);
    } else {
        float* ws   = (float*)d_ws;
        float* fx   = ws;
        float* gx   = fx + BNF;
        float* hx   = gx + BNF;
        float* linv = hx + BNF;
        float* o    = linv + BN;
        k_proj  <<<dim3(BN / 32, 3), 256, 0, stream>>>(x, Wf, bf, Wg, bg, Wh, bh, fx, gx, hx);
        k_stats <<<BN / 64, 256, 0, stream>>>(fx, gx, linv);
        k_attnpv<<<BN / 64, 256, 0, stream>>>(fx, gx, hx, linv, o);
        k_final <<<BN / 32, 256, 0, stream>>>(o, Wv, bv, out);
    }
}